// Round 2
// baseline (195.914 us; speedup 1.0000x reference)
//
#include <hip/hip_runtime.h>
#include <hip/hip_bf16.h>
#include <math.h>

#define B_ 2
#define TX_ 1024
#define TY_ 4096
#define C_ 768
#define H_ 12
#define D_ 64
#define NSPLIT 4
#define R_ (B_ * H_ * TX_)

typedef __bf16 bf16x8 __attribute__((ext_vector_type(8)));
typedef float floatx4 __attribute__((ext_vector_type(4)));

__device__ __forceinline__ void async_copy16(const void* g, void* l) {
    __builtin_amdgcn_global_load_lds(
        (const __attribute__((address_space(1))) unsigned int*)g,
        (__attribute__((address_space(3))) unsigned int*)l,
        16, 0, 0);
}

__device__ __forceinline__ bf16x8 cvt8(const float* s) {
    bf16x8 r;
#pragma unroll
    for (int i = 0; i < 8; i++) r[i] = (__bf16)s[i];
    return r;
}

// ---------------------------------------------------------------------------
// prep: ONE launch: (a) 3 weight transposes W(768xN f32)->Wt(Nx768 bf16),
// (b) x,y f32->bf16 conversion (8 elems/thread).
// ---------------------------------------------------------------------------
__global__ __launch_bounds__(256)
void prep(const float* __restrict__ x,  __bf16* __restrict__ xb,
          const float* __restrict__ y,  __bf16* __restrict__ yb,
          const float* __restrict__ Wq, __bf16* __restrict__ Wqt,
          const float* __restrict__ Wkv,__bf16* __restrict__ Wkvt,
          const float* __restrict__ Wpr,__bf16* __restrict__ Wprt)
{
    __shared__ float tile[32][33];
    const int bid = blockIdx.x;
    if (bid >= 2304) {
        const int cb = bid - 2304;
        const float* src; __bf16* dst; size_t base;
        if (cb < 768) { src = x; dst = xb; base = (size_t)cb * 2048; }
        else          { src = y; dst = yb; base = (size_t)(cb - 768) * 2048; }
        const size_t i = base + threadIdx.x * 8;
        float4 v0 = *(const float4*)(src + i);
        float4 v1 = *(const float4*)(src + i + 4);
        bf16x8 p;
        p[0] = (__bf16)v0.x; p[1] = (__bf16)v0.y; p[2] = (__bf16)v0.z; p[3] = (__bf16)v0.w;
        p[4] = (__bf16)v1.x; p[5] = (__bf16)v1.y; p[6] = (__bf16)v1.z; p[7] = (__bf16)v1.w;
        *(bf16x8*)(dst + i) = p;
        return;
    }
    const int bxr = bid % 96;
    const int byr = bid / 96;
    const float* W; __bf16* Wt; int N, nb; float scale = 1.0f;
    if (bxr < 24)      { W = Wq;  Wt = Wqt;  N = C_;     nb = bxr;      scale = 0.125f; }
    else if (bxr < 72) { W = Wkv; Wt = Wkvt; N = 2 * C_; nb = bxr - 24; }
    else               { W = Wpr; Wt = Wprt; N = C_;     nb = bxr - 72; }
    const int bx = nb * 32;
    const int by = byr * 32;
    const int tx = threadIdx.x & 31, ty = threadIdx.x >> 5;
#pragma unroll
    for (int i = 0; i < 4; i++)
        tile[ty + i * 8][tx] = W[(size_t)(by + ty + i * 8) * N + bx + tx];
    __syncthreads();
#pragma unroll
    for (int i = 0; i < 4; i++)
        Wt[(size_t)(bx + ty + i * 8) * C_ + by + tx] =
            (__bf16)(tile[tx][ty + i * 8] * scale);
}

// ---------------------------------------------------------------------------
// Fused Q + KV MFMA GEMM, 1D grid 864 blocks (96 Q tiles first, 768 KV).
// 128x128 tile (2x the MFMA per barrier and 1.5x the MFMA/ds_read of the old
// 64x128). K-loop: 24 chunks of 32-k, 3 rotating 16KB LDS buffers (48KB ->
// 3 blocks/CU), counted s_waitcnt vmcnt(4) -- next chunk's 4 loads stay in
// flight across the barrier.
// Wave layout: 2x2, each wave 64 rows x 64 cols -> acc[4][4].
//   bid <  96: Q : rope -> Qbh [bh][TX][64]
//   bid >= 96: KV: n0<C_ rope -> Kbh [bh][TY][64]; n0>=C_ -> Vtb [bh][64][TY]
// ---------------------------------------------------------------------------
__global__ __launch_bounds__(256)
void gemm_qkv(const __bf16* __restrict__ xb, const __bf16* __restrict__ Wqt,
              const __bf16* __restrict__ yb, const __bf16* __restrict__ Wkvt,
              __bf16* __restrict__ Qbh, __bf16* __restrict__ Kbh,
              __bf16* __restrict__ Vtb,
              const float* __restrict__ x_t, const float* __restrict__ y_t,
              const float* __restrict__ inv_freq)
{
    const int bid = blockIdx.x;
    const bool isQ = (bid < 96);
    const __bf16* A; const __bf16* Bt; const float* t_arr;
    int row0, n0, T, TSH;
    if (isQ) {
        A = xb; Bt = Wqt; t_arr = x_t;
        row0 = (bid / 6) * 128; n0 = (bid % 6) * 128; T = TX_; TSH = 10;
    } else {
        const int r = bid - 96;
        A = yb; Bt = Wkvt; t_arr = y_t;
        row0 = (r / 12) * 128; n0 = (r % 12) * 128; T = TY_; TSH = 12;
    }
    const bool isV = (!isQ) && (n0 >= C_);

    // 3 pipeline buffers x 16KB (8KB A + 8KB B) = 49152 B
    __shared__ __align__(16) float smem_f[12288];
    __bf16* smem_b = (__bf16*)smem_f;

    const int tid  = threadIdx.x;
    const int wave = tid >> 6;
    const int lane = tid & 63;
    const int m16  = lane & 15;
    const int quad = lane >> 4;
    const int wm   = wave >> 1;
    const int wn   = wave & 1;

    floatx4 acc[4][4];
#pragma unroll
    for (int i = 0; i < 4; i++)
#pragma unroll
        for (int j = 0; j < 4; j++) acc[i][j] = (floatx4){0.f, 0.f, 0.f, 0.f};

    // staging: A 128x32 bf16 = 8KB (2 issues), B 128x32 = 8KB (2 issues)
    int sr[2], sc[2];
#pragma unroll
    for (int j = 0; j < 2; j++) {
        const int e = j * 2048 + wave * 512 + lane * 8;
        sr[j] = e >> 5; sc[j] = e & 31;
    }

    auto stage = [&](int chunk, int buf) {
        const int kk = chunk * 32;
#pragma unroll
        for (int j = 0; j < 2; j++)
            async_copy16(A + (size_t)(row0 + sr[j]) * C_ + (kk + sc[j]),
                         (char*)smem_f + buf * 16384 + j * 4096 + wave * 1024);
#pragma unroll
        for (int j = 0; j < 2; j++)
            async_copy16(Bt + (size_t)(n0 + sr[j]) * C_ + (kk + sc[j]),
                         (char*)smem_f + buf * 16384 + 8192 + j * 4096 + wave * 1024);
    };

    // prologue: chunks 0,1 in flight (4 loads each per wave)
    stage(0, 0);
    stage(1, 1);

    int cur = 0;
    for (int t = 0; t < 24; ++t) {
        // wait for chunk t (own 4 loads); chunk t+1's 4 may stay in flight
        if (t < 23) asm volatile("s_waitcnt vmcnt(4)" ::: "memory");
        else        asm volatile("s_waitcnt vmcnt(0)" ::: "memory");
        __builtin_amdgcn_s_barrier();
        asm volatile("" ::: "memory");

        if (t + 2 < 24) {
            int nb = cur + 2; if (nb >= 3) nb -= 3;
            stage(t + 2, nb);   // buffer last read at iter t-1, before this barrier
        }

        const __bf16* As = smem_b + cur * 8192;
        const __bf16* Bs = As + 4096;
        bf16x8 af[4], bfr[4];
#pragma unroll
        for (int i = 0; i < 4; i++)
            af[i] = *(const bf16x8*)(As + (size_t)(wm * 64 + i * 16 + m16) * 32 + quad * 8);
#pragma unroll
        for (int j = 0; j < 4; j++)
            bfr[j] = *(const bf16x8*)(Bs + (size_t)(wn * 64 + j * 16 + m16) * 32 + quad * 8);
#pragma unroll
        for (int i = 0; i < 4; i++)
#pragma unroll
            for (int j = 0; j < 4; j++)
                acc[i][j] = __builtin_amdgcn_mfma_f32_16x16x32_bf16(af[i], bfr[j], acc[i][j], 0, 0, 0);

        cur = (cur == 2) ? 0 : cur + 1;
    }

    // ---- epilogue (LDS-staged, full-line stores), i in {0..3}: 32 rows each
    // fs row (wm*16 + row_l) holds global row (row0 + wm*64 + i*16 + row_l)
    const int STR = 132;
    float* fs = smem_f;

#pragma unroll
    for (int i = 0; i < 4; i++) {
        __syncthreads();
#pragma unroll
        for (int j = 0; j < 4; j++) {
            const int col_l = wn * 64 + j * 16 + m16;
#pragma unroll
            for (int r = 0; r < 4; r++) {
                const int row_l = quad * 4 + r;
                float v = acc[i][j][r];
                if (!isV) {
                    const float vp = __shfl_xor(v, 1);
                    const int row = row0 + wm * 64 + i * 16 + row_l;
                    const int cc = (n0 + col_l) & (D_ - 1);
                    const float fr = t_arr[row] * inv_freq[cc >> 1];
                    const float sn = __sinf(fr), cs = __cosf(fr);
                    v = (m16 & 1) ? (v * cs + vp * sn) : (v * cs - vp * sn);
                }
                fs[(wm * 16 + row_l) * STR + col_l] = v;
            }
        }
        __syncthreads();

        if (!isV) {
            __bf16* outb = isQ ? Qbh : Kbh;
            const int r32 = tid >> 3;                 // 0..31 (fs row)
            const int lane8 = tid & 7;
            const int grow = row0 + (r32 >> 4) * 64 + i * 16 + (r32 & 15);
            const int bb = grow >> TSH;
            const int rk = grow & (T - 1);
            const int h  = (n0 >> 6) + (lane8 >> 2);
            const int d0 = (lane8 & 3) * 16;
            __bf16* gp = outb + ((size_t)(bb * H_ + h) * T + rk) * 64 + d0;
            const float* sp = &fs[r32 * STR + lane8 * 16];
            *(bf16x8*)gp       = cvt8(sp);
            *(bf16x8*)(gp + 8) = cvt8(sp + 8);
        } else {
            const int dcol = tid >> 1;                // 0..127
            const int g16  = tid & 1;                 // 16-row group (fs rows)
            const int h  = ((n0 - C_) >> 6) + (dcol >> 6);
            const int dd = dcol & 63;
            const int kbase = row0 + g16 * 64 + i * 16;
            const int bb  = kbase >> 12;
            const int kin = kbase & (TY_ - 1);
            float tmp[16];
#pragma unroll
            for (int jj = 0; jj < 16; jj++)
                tmp[jj] = fs[(g16 * 16 + jj) * STR + dcol];
            __bf16* gp = Vtb + ((size_t)(bb * H_ + h) * 64 + dd) * TY_ + kin;
            *(bf16x8*)gp       = cvt8(tmp);
            *(bf16x8*)(gp + 8) = cvt8(tmp + 8);
        }
    }
}

// ---------------------------------------------------------------------------
// MFMA flash attention (round-8 proven version): LDS-staged 32-k chunks,
// no-max softmax, block = 4 waves = 64 q rows, NSPLIT k-splits.
// ---------------------------------------------------------------------------
__global__ __launch_bounds__(256)
void attn_mfma(const __bf16* __restrict__ Qb,
               const __bf16* __restrict__ Kb,
               const __bf16* __restrict__ Vt,
               const float* __restrict__ x_t,
               const float* __restrict__ y_t,
               const int* __restrict__ dist_p,
               const int* __restrict__ min_dist_p,
               float* __restrict__ pacc,
               float* __restrict__ pml)
{
    __shared__ __align__(16) __bf16 Kc[32 * 64];
    __shared__ __align__(16) __bf16 Vc[64 * 32];
    __shared__ __align__(16) __bf16 Pt[4][16 * 32];

    const int tid  = threadIdx.x;
    const int wave = tid >> 6;
    const int m16  = tid & 15;
    const int quad = (tid & 63) >> 4;
    const int qt = blockIdx.x, bh = blockIdx.y, split = blockIdx.z;
    const int b = bh / H_;
    const int qblk  = qt * 64;
    const int qbase = qblk + wave * 16;

    const float dist = (float)dist_p[0];
    const float md   = (float)min_dist_p[0];
    const float* yt = y_t + (size_t)b * TY_;
    const float* xt = x_t + (size_t)b * TX_;

    const float xtmin = xt[qblk] - md;
    const float xtmax = xt[qblk + 63] - md;
    int lo = 0, hi = TY_;
    while (lo < hi) { int mid = (lo + hi) >> 1; if (yt[mid] + dist < xtmin) lo = mid + 1; else hi = mid; }
    const int klo = lo;
    lo = 0; hi = TY_;
    while (lo < hi) { int mid = (lo + hi) >> 1; if (yt[mid] <= xtmax) lo = mid + 1; else hi = mid; }
    const int khi = lo - 1;
    const int len = khi - klo + 1;

    int k0 = klo, k1 = klo;
    if (len > 0) {
        const int cnt = (len + NSPLIT - 1) / NSPLIT;
        k0 = klo + split * cnt;
        k1 = min(k0 + cnt, klo + len);
    }

    float xtq[4];
#pragma unroll
    for (int r = 0; r < 4; r++)
        xtq[r] = xt[qbase + quad * 4 + r] - md;

    const __bf16* qp = Qb + ((size_t)bh * TX_ + qbase + m16) * 64;
    const bf16x8 aq0 = *(const bf16x8*)(qp + quad * 8);
    const bf16x8 aq1 = *(const bf16x8*)(qp + 32 + quad * 8);

    float l[4];
    floatx4 o[4];
#pragma unroll
    for (int r = 0; r < 4; r++) l[r] = 0.f;
#pragma unroll
    for (int t = 0; t < 4; t++) o[t] = (floatx4){0.f, 0.f, 0.f, 0.f};

    for (int kc = k0; kc < k1; kc += 32) {
        const float yt0 = yt[min(kc + m16, TY_ - 1)];
        const float yt1 = yt[min(kc + 16 + m16, TY_ - 1)];

        __syncthreads();
        {
            const int krow = tid >> 3;
            const int kg = min(kc + krow, TY_ - 1);
            async_copy16(Kb + ((size_t)bh * TY_ + kg) * 64 + (tid & 7) * 8,
                         (char*)Kc + tid * 16);
            const int d = tid >> 2;
            const int kv = min(kc + (tid & 3) * 8, TY_ - 8);
            async_copy16(Vt + ((size_t)bh * 64 + d) * TY_ + kv,
                         (char*)Vc + tid * 16);
        }
        __syncthreads();

        const bf16x8 bk0h0 = *(const bf16x8*)(Kc + m16 * 64 + quad * 8);
        const bf16x8 bk1h0 = *(const bf16x8*)(Kc + m16 * 64 + 32 + quad * 8);
        const bf16x8 bk0h1 = *(const bf16x8*)(Kc + (16 + m16) * 64 + quad * 8);
        const bf16x8 bk1h1 = *(const bf16x8*)(Kc + (16 + m16) * 64 + 32 + quad * 8);
        floatx4 s0 = (floatx4){0.f, 0.f, 0.f, 0.f};
        floatx4 s1 = (floatx4){0.f, 0.f, 0.f, 0.f};
        s0 = __builtin_amdgcn_mfma_f32_16x16x32_bf16(aq0, bk0h0, s0, 0, 0, 0);
        s0 = __builtin_amdgcn_mfma_f32_16x16x32_bf16(aq1, bk1h0, s0, 0, 0, 0);
        s1 = __builtin_amdgcn_mfma_f32_16x16x32_bf16(aq0, bk0h1, s1, 0, 0, 0);
        s1 = __builtin_amdgcn_mfma_f32_16x16x32_bf16(aq1, bk1h1, s1, 0, 0, 0);

        const int kg0 = kc + m16;
        const int kg1 = kc + 16 + m16;
        __bf16* pt = Pt[wave];
#pragma unroll
        for (int r = 0; r < 4; r++) {
            const bool v0 = (kg0 < k1) && (xtq[r] >= yt0) && (xtq[r] <= yt0 + dist);
            const bool v1 = (kg1 < k1) && (xtq[r] >= yt1) && (xtq[r] <= yt1 + dist);
            const float p0 = v0 ? (float)(__bf16)__expf(s0[r]) : 0.f;
            const float p1 = v1 ? (float)(__bf16)__expf(s1[r]) : 0.f;
            l[r] += p0 + p1;
            pt[(quad * 4 + r) * 32 + m16]      = (__bf16)p0;
            pt[(quad * 4 + r) * 32 + 16 + m16] = (__bf16)p1;
        }
        const bf16x8 ap = *(const bf16x8*)(pt + m16 * 32 + quad * 8);
#pragma unroll
        for (int t = 0; t < 4; t++) {
            const bf16x8 bv = *(const bf16x8*)(Vc + (t * 16 + m16) * 32 + quad * 8);
            o[t] = __builtin_amdgcn_mfma_f32_16x16x32_bf16(ap, bv, o[t], 0, 0, 0);
        }
    }

#pragma unroll
    for (int r = 0; r < 4; r++) {
#pragma unroll
        for (int w = 1; w < 16; w <<= 1)
            l[r] += __shfl_xor(l[r], w);
    }

#pragma unroll
    for (int t = 0; t < 4; t++)
#pragma unroll
        for (int r = 0; r < 4; r++) {
            const size_t gr = (size_t)bh * TX_ + qbase + quad * 4 + r;
            pacc[((size_t)split * R_ + gr) * 64 + t * 16 + m16] = o[t][r];
        }
    if (m16 == 0) {
#pragma unroll
        for (int r = 0; r < 4; r++) {
            const size_t gr = (size_t)bh * TX_ + qbase + quad * 4 + r;
            pml[(size_t)split * R_ + gr] = l[r];
        }
    }
}

// ---------------------------------------------------------------------------
// Combine NSPLIT partials -> Ob bf16 (B,TX,C)
// ---------------------------------------------------------------------------
__global__ __launch_bounds__(256)
void combine_kernel(const float* __restrict__ pacc,
                    const float* __restrict__ pml,
                    __bf16* __restrict__ O)
{
    const int d   = threadIdx.x;
    const int sub = threadIdx.y;
    const size_t r = (size_t)blockIdx.x * 4 + sub;
    const int bh  = (int)(r / TX_);
    const int txg = (int)(r % TX_);
    const int b = bh / H_, h = bh % H_;

    float L = 0.f, val = 0.f;
#pragma unroll
    for (int s = 0; s < NSPLIT; s++) {
        L   += pml[(size_t)s * R_ + r];
        val += pacc[((size_t)s * R_ + r) * 64 + d];
    }
    const float o = (L > 0.f) ? val / L : 0.f;
    O[(size_t)(b * TX_ + txg) * C_ + h * D_ + d] = (__bf16)o;
}

// ---------------------------------------------------------------------------
// proj GEMM: out(M,768 f32) = A(M,768 bf16) @ Bt(768,768 bf16)^T
// 128x128 tile. Pipelined: 24 chunks of 32-k, 3 rotating 16KB buffers (48KB),
// counted vmcnt(4). Only 96 blocks -> in-block pipelining is the only
// latency hiding available.
// ---------------------------------------------------------------------------
__global__ __launch_bounds__(256)
void gemm_proj(const __bf16* __restrict__ A,
               const __bf16* __restrict__ Bt,
               float* __restrict__ out0)
{
    __shared__ __align__(16) float smem_f[12288];   // 49152 B
    __bf16* smem_b = (__bf16*)smem_f;

    const int tid  = threadIdx.x;
    const int wave = tid >> 6;
    const int lane = tid & 63;
    const int m16  = lane & 15;
    const int quad = lane >> 4;
    const int wm   = wave >> 1;
    const int wn   = wave & 1;
    const int row0 = blockIdx.y * 128;
    const int n0   = blockIdx.x * 128;

    floatx4 acc[4][4];
#pragma unroll
    for (int i = 0; i < 4; i++)
#pragma unroll
        for (int j = 0; j < 4; j++) acc[i][j] = (floatx4){0.f, 0.f, 0.f, 0.f};

    int srow[4], scol[4];
#pragma unroll
    for (int j = 0; j < 4; j++) {
        int e = j * 2048 + wave * 512 + lane * 8;
        int e2 = e & 4095;
        srow[j] = e2 >> 5;
        scol[j] = e2 & 31;
    }

    auto stage = [&](int chunk, int buf) {
        const int kk = chunk * 32;
#pragma unroll
        for (int j = 0; j < 4; j++) {
            const __bf16* src = (j < 2)
                ? A  + (size_t)(row0 + srow[j]) * C_ + (kk + scol[j])
                : Bt + (size_t)(n0   + srow[j]) * C_ + (kk + scol[j]);
            async_copy16(src, (char*)smem_f + buf * 16384 + j * 4096 + wave * 1024);
        }
    };

    stage(0, 0);
    stage(1, 1);

    int cur = 0;
    for (int t = 0; t < 24; ++t) {
        if (t < 23) asm volatile("s_waitcnt vmcnt(4)" ::: "memory");
        else        asm volatile("s_waitcnt vmcnt(0)" ::: "memory");
        __builtin_amdgcn_s_barrier();
        asm volatile("" ::: "memory");

        if (t + 2 < 24) {
            int nb = cur + 2; if (nb >= 3) nb -= 3;
            stage(t + 2, nb);
        }

        const __bf16* As = smem_b + cur * 8192;
        const __bf16* Bs = As + 4096;
        bf16x8 af[4], bfr[4];
#pragma unroll
        for (int i = 0; i < 4; i++)
            af[i] = *(const bf16x8*)(As + (size_t)(wm * 64 + i * 16 + m16) * 32 + quad * 8);
#pragma unroll
        for (int j = 0; j < 4; j++)
            bfr[j] = *(const bf16x8*)(Bs + (size_t)(wn * 64 + j * 16 + m16) * 32 + quad * 8);
#pragma unroll
        for (int i = 0; i < 4; i++)
#pragma unroll
            for (int j = 0; j < 4; j++)
                acc[i][j] = __builtin_amdgcn_mfma_f32_16x16x32_bf16(af[i], bfr[j], acc[i][j], 0, 0, 0);

        cur = (cur == 2) ? 0 : cur + 1;
    }

    const int STR = 132;
    float* fs = smem_f;
#pragma unroll
    for (int i = 0; i < 4; i++) {
        __syncthreads();
#pragma unroll
        for (int j = 0; j < 4; j++) {
            const int col_l = wn * 64 + j * 16 + m16;
#pragma unroll
            for (int r = 0; r < 4; r++)
                fs[(wm * 16 + quad * 4 + r) * STR + col_l] = acc[i][j][r];
        }
        __syncthreads();
        const int r32 = tid >> 3;
        const int lc  = (tid & 7) * 4;
        const int row = row0 + (r32 >> 4) * 64 + i * 16 + (r32 & 15);
        float* gp = out0 + (size_t)row * C_ + n0;
#pragma unroll
        for (int c2 = 0; c2 < 4; c2++) {
            float4 v4 = *(const float4*)&fs[r32 * STR + c2 * 32 + lc];
            *(float4*)(gp + c2 * 32 + lc) = v4;
        }
    }
}

// ---------------------------------------------------------------------------
extern "C" void kernel_launch(void* const* d_in, const int* in_sizes, int n_in,
                              void* d_out, int out_size, void* d_ws, size_t ws_size,
                              hipStream_t stream)
{
    const float* x        = (const float*)d_in[0];
    const float* x_t      = (const float*)d_in[1];
    const float* y        = (const float*)d_in[2];
    const float* y_t      = (const float*)d_in[3];
    const int*   dist     = (const int*)d_in[4];
    const int*   min_dist = (const int*)d_in[5];
    const float* Wq       = (const float*)d_in[6];
    const float* Wkv      = (const float*)d_in[7];
    const float* Wproj    = (const float*)d_in[8];
    const float* inv_freq = (const float*)d_in[9];
    float* out = (float*)d_out;

    const size_t QN = (size_t)B_ * TX_ * C_;
    const size_t KN = (size_t)B_ * TY_ * C_;

    float* ws = (float*)d_ws;
    float* pacc = ws; ws += (size_t)NSPLIT * R_ * 64;
    float* pml  = ws; ws += (size_t)NSPLIT * R_;
    __bf16* bws = (__bf16*)ws;
    __bf16* xb    = bws; bws += QN;
    __bf16* yb    = bws; bws += KN;
    __bf16* Wqt   = bws; bws += (size_t)C_ * C_;
    __bf16* Wkvt  = bws; bws += (size_t)C_ * 2 * C_;
    __bf16* Wprt  = bws; bws += (size_t)C_ * C_;
    __bf16* Ob    = bws; bws += QN;
    __bf16* Qbh   = bws; bws += QN;          // [bh][TX][64]
    __bf16* Kbh   = bws; bws += KN;          // [bh][TY][64]
    __bf16* Vtb   = bws; bws += KN + 128;    // [bh][64][TY]

    prep<<<dim3(2304 + 3840), dim3(256), 0, stream>>>(
        x, xb, y, yb, Wq, Wqt, Wkv, Wkvt, Wproj, Wprt);

    gemm_qkv<<<dim3(864), dim3(256), 0, stream>>>(
        xb, Wqt, yb, Wkvt, Qbh, Kbh, Vtb, x_t, y_t, inv_freq);

    attn_mfma<<<dim3(TX_ / 64, B_ * H_, NSPLIT), dim3(256), 0, stream>>>(
        Qbh, Kbh, Vtb, x_t, y_t, dist, min_dist, pacc, pml);

    combine_kernel<<<dim3((unsigned)(R_ / 4)), dim3(64, 4), 0, stream>>>(
        pacc, pml, Ob);

    gemm_proj<<<dim3(C_ / 128, (B_ * TX_) / 128), dim3(256), 0, stream>>>(
        Ob, Wprt, out);
}

// Round 3
// 194.954 us; speedup vs baseline: 1.0049x; 1.0049x over previous
//
#include <hip/hip_runtime.h>
#include <hip/hip_bf16.h>
#include <math.h>

#define B_ 2
#define TX_ 1024
#define TY_ 4096
#define C_ 768
#define H_ 12
#define D_ 64
#define NSPLIT 4
#define R_ (B_ * H_ * TX_)

typedef __bf16 bf16x8 __attribute__((ext_vector_type(8)));
typedef float floatx4 __attribute__((ext_vector_type(4)));

__device__ __forceinline__ void async_copy16(const void* g, void* l) {
    __builtin_amdgcn_global_load_lds(
        (const __attribute__((address_space(1))) unsigned int*)g,
        (__attribute__((address_space(3))) unsigned int*)l,
        16, 0, 0);
}

__device__ __forceinline__ bf16x8 cvt8(const float* s) {
    bf16x8 r;
#pragma unroll
    for (int i = 0; i < 8; i++) r[i] = (__bf16)s[i];
    return r;
}

// ---------------------------------------------------------------------------
// prep: ONE launch: (a) 3 weight transposes W(768xN f32)->Wt(Nx768 bf16),
// (b) x,y f32->bf16 conversion (8 elems/thread).
// ---------------------------------------------------------------------------
__global__ __launch_bounds__(256)
void prep(const float* __restrict__ x,  __bf16* __restrict__ xb,
          const float* __restrict__ y,  __bf16* __restrict__ yb,
          const float* __restrict__ Wq, __bf16* __restrict__ Wqt,
          const float* __restrict__ Wkv,__bf16* __restrict__ Wkvt,
          const float* __restrict__ Wpr,__bf16* __restrict__ Wprt)
{
    __shared__ float tile[32][33];
    const int bid = blockIdx.x;
    if (bid >= 2304) {
        const int cb = bid - 2304;
        const float* src; __bf16* dst; size_t base;
        if (cb < 768) { src = x; dst = xb; base = (size_t)cb * 2048; }
        else          { src = y; dst = yb; base = (size_t)(cb - 768) * 2048; }
        const size_t i = base + threadIdx.x * 8;
        float4 v0 = *(const float4*)(src + i);
        float4 v1 = *(const float4*)(src + i + 4);
        bf16x8 p;
        p[0] = (__bf16)v0.x; p[1] = (__bf16)v0.y; p[2] = (__bf16)v0.z; p[3] = (__bf16)v0.w;
        p[4] = (__bf16)v1.x; p[5] = (__bf16)v1.y; p[6] = (__bf16)v1.z; p[7] = (__bf16)v1.w;
        *(bf16x8*)(dst + i) = p;
        return;
    }
    const int bxr = bid % 96;
    const int byr = bid / 96;
    const float* W; __bf16* Wt; int N, nb; float scale = 1.0f;
    if (bxr < 24)      { W = Wq;  Wt = Wqt;  N = C_;     nb = bxr;      scale = 0.125f; }
    else if (bxr < 72) { W = Wkv; Wt = Wkvt; N = 2 * C_; nb = bxr - 24; }
    else               { W = Wpr; Wt = Wprt; N = C_;     nb = bxr - 72; }
    const int bx = nb * 32;
    const int by = byr * 32;
    const int tx = threadIdx.x & 31, ty = threadIdx.x >> 5;
#pragma unroll
    for (int i = 0; i < 4; i++)
        tile[ty + i * 8][tx] = W[(size_t)(by + ty + i * 8) * N + bx + tx];
    __syncthreads();
#pragma unroll
    for (int i = 0; i < 4; i++)
        Wt[(size_t)(bx + ty + i * 8) * C_ + by + tx] =
            (__bf16)(tile[tx][ty + i * 8] * scale);
}

// ---------------------------------------------------------------------------
// Fused Q + KV MFMA GEMM, 1D grid 864 blocks (96 Q tiles first, 768 KV).
// 128x128 tile. SINGLE-BATCH design: 2 rotating 16KB LDS buffers = 32KB ->
// 4 blocks/CU resident -> 1024 slots >= 864 blocks, no tail batch (rounds
// 0-2 all ran a ~2x makespan from a nearly-empty second block batch).
// Pipeline: stage(t+1) issued BEFORE waiting on chunk t (depth-2 in flight),
// counted s_waitcnt vmcnt(4) in the steady state. XCD-bijective swizzle
// (864%8==0) so consecutive work-ids (n-fastest, shared A panel) share L2.
// Wave layout: 2x2, each wave 64 rows x 64 cols -> acc[4][4].
//   bid <  96: Q : rope -> Qbh [bh][TX][64]
//   bid >= 96: KV: n0<C_ rope -> Kbh [bh][TY][64]; n0>=C_ -> Vtb [bh][64][TY]
// ---------------------------------------------------------------------------
__global__ __launch_bounds__(256)
void gemm_qkv(const __bf16* __restrict__ xb, const __bf16* __restrict__ Wqt,
              const __bf16* __restrict__ yb, const __bf16* __restrict__ Wkvt,
              __bf16* __restrict__ Qbh, __bf16* __restrict__ Kbh,
              __bf16* __restrict__ Vtb,
              const float* __restrict__ x_t, const float* __restrict__ y_t,
              const float* __restrict__ inv_freq)
{
    // bijective XCD swizzle: 864 = 8 * 108
    const int bid = (blockIdx.x & 7) * 108 + (blockIdx.x >> 3);
    const bool isQ = (bid < 96);
    const __bf16* A; const __bf16* Bt; const float* t_arr;
    int row0, n0, T, TSH;
    if (isQ) {
        A = xb; Bt = Wqt; t_arr = x_t;
        row0 = (bid / 6) * 128; n0 = (bid % 6) * 128; T = TX_; TSH = 10;
    } else {
        const int r = bid - 96;
        A = yb; Bt = Wkvt; t_arr = y_t;
        row0 = (r / 12) * 128; n0 = (r % 12) * 128; T = TY_; TSH = 12;
    }
    const bool isV = (!isQ) && (n0 >= C_);

    // 2 pipeline buffers x 16KB (8KB A + 8KB B) = 32768 B -> 4 blocks/CU
    __shared__ __align__(16) float smem_f[8192];
    __bf16* smem_b = (__bf16*)smem_f;

    const int tid  = threadIdx.x;
    const int wave = tid >> 6;
    const int lane = tid & 63;
    const int m16  = lane & 15;
    const int quad = lane >> 4;
    const int wm   = wave >> 1;
    const int wn   = wave & 1;

    floatx4 acc[4][4];
#pragma unroll
    for (int i = 0; i < 4; i++)
#pragma unroll
        for (int j = 0; j < 4; j++) acc[i][j] = (floatx4){0.f, 0.f, 0.f, 0.f};

    // staging: A 128x32 bf16 = 8KB (2 issues/wave), B 128x32 = 8KB (2 issues)
    int sr[2], sc[2];
#pragma unroll
    for (int j = 0; j < 2; j++) {
        const int e = j * 2048 + wave * 512 + lane * 8;
        sr[j] = e >> 5; sc[j] = e & 31;
    }

    auto stage = [&](int chunk, int buf) {
        const int kk = chunk * 32;
#pragma unroll
        for (int j = 0; j < 2; j++)
            async_copy16(A + (size_t)(row0 + sr[j]) * C_ + (kk + sc[j]),
                         (char*)smem_f + buf * 16384 + j * 4096 + wave * 1024);
#pragma unroll
        for (int j = 0; j < 2; j++)
            async_copy16(Bt + (size_t)(n0 + sr[j]) * C_ + (kk + sc[j]),
                         (char*)smem_f + buf * 16384 + 8192 + j * 4096 + wave * 1024);
    };

    // prologue: chunk 0 in flight
    stage(0, 0);

    for (int t = 0; t < 24; ++t) {
        // issue next chunk first (max overlap), then wait for chunk t only
        if (t + 1 < 24) {
            stage(t + 1, (t + 1) & 1);
            asm volatile("s_waitcnt vmcnt(4)" ::: "memory");
        } else {
            asm volatile("s_waitcnt vmcnt(0)" ::: "memory");
        }
        __builtin_amdgcn_s_barrier();
        asm volatile("" ::: "memory");

        const __bf16* As = smem_b + (t & 1) * 8192;
        const __bf16* Bs = As + 4096;
        bf16x8 af[4], bfr[4];
#pragma unroll
        for (int i = 0; i < 4; i++)
            af[i] = *(const bf16x8*)(As + (size_t)(wm * 64 + i * 16 + m16) * 32 + quad * 8);
#pragma unroll
        for (int j = 0; j < 4; j++)
            bfr[j] = *(const bf16x8*)(Bs + (size_t)(wn * 64 + j * 16 + m16) * 32 + quad * 8);
#pragma unroll
        for (int i = 0; i < 4; i++)
#pragma unroll
            for (int j = 0; j < 4; j++)
                acc[i][j] = __builtin_amdgcn_mfma_f32_16x16x32_bf16(af[i], bfr[j], acc[i][j], 0, 0, 0);

        // all LDS reads of buf (t&1) must retire before iter t+1 stages
        // chunk t+2 into it
        asm volatile("s_waitcnt lgkmcnt(0)" ::: "memory");
        __builtin_amdgcn_s_barrier();
        asm volatile("" ::: "memory");
    }

    // ---- epilogue (LDS-staged, full-line stores), i in {0..3}: 32 rows each
    // fs row (wm*16 + row_l) holds global row (row0 + wm*64 + i*16 + row_l)
    const int STR = 132;
    float* fs = smem_f;

#pragma unroll
    for (int i = 0; i < 4; i++) {
        __syncthreads();
#pragma unroll
        for (int j = 0; j < 4; j++) {
            const int col_l = wn * 64 + j * 16 + m16;
#pragma unroll
            for (int r = 0; r < 4; r++) {
                const int row_l = quad * 4 + r;
                float v = acc[i][j][r];
                if (!isV) {
                    const float vp = __shfl_xor(v, 1);
                    const int row = row0 + wm * 64 + i * 16 + row_l;
                    const int cc = (n0 + col_l) & (D_ - 1);
                    const float fr = t_arr[row] * inv_freq[cc >> 1];
                    const float sn = __sinf(fr), cs = __cosf(fr);
                    v = (m16 & 1) ? (v * cs + vp * sn) : (v * cs - vp * sn);
                }
                fs[(wm * 16 + row_l) * STR + col_l] = v;
            }
        }
        __syncthreads();

        if (!isV) {
            __bf16* outb = isQ ? Qbh : Kbh;
            const int r32 = tid >> 3;                 // 0..31 (fs row)
            const int lane8 = tid & 7;
            const int grow = row0 + (r32 >> 4) * 64 + i * 16 + (r32 & 15);
            const int bb = grow >> TSH;
            const int rk = grow & (T - 1);
            const int h  = (n0 >> 6) + (lane8 >> 2);
            const int d0 = (lane8 & 3) * 16;
            __bf16* gp = outb + ((size_t)(bb * H_ + h) * T + rk) * 64 + d0;
            const float* sp = &fs[r32 * STR + lane8 * 16];
            *(bf16x8*)gp       = cvt8(sp);
            *(bf16x8*)(gp + 8) = cvt8(sp + 8);
        } else {
            const int dcol = tid >> 1;                // 0..127
            const int g16  = tid & 1;                 // 16-row group (fs rows)
            const int h  = ((n0 - C_) >> 6) + (dcol >> 6);
            const int dd = dcol & 63;
            const int kbase = row0 + g16 * 64 + i * 16;
            const int bb  = kbase >> 12;
            const int kin = kbase & (TY_ - 1);
            float tmp[16];
#pragma unroll
            for (int jj = 0; jj < 16; jj++)
                tmp[jj] = fs[(g16 * 16 + jj) * STR + dcol];
            __bf16* gp = Vtb + ((size_t)(bb * H_ + h) * 64 + dd) * TY_ + kin;
            *(bf16x8*)gp       = cvt8(tmp);
            *(bf16x8*)(gp + 8) = cvt8(tmp + 8);
        }
    }
}

// ---------------------------------------------------------------------------
// MFMA flash attention (round-8 proven version): LDS-staged 32-k chunks,
// no-max softmax, block = 4 waves = 64 q rows, NSPLIT k-splits.
// ---------------------------------------------------------------------------
__global__ __launch_bounds__(256)
void attn_mfma(const __bf16* __restrict__ Qb,
               const __bf16* __restrict__ Kb,
               const __bf16* __restrict__ Vt,
               const float* __restrict__ x_t,
               const float* __restrict__ y_t,
               const int* __restrict__ dist_p,
               const int* __restrict__ min_dist_p,
               float* __restrict__ pacc,
               float* __restrict__ pml)
{
    __shared__ __align__(16) __bf16 Kc[32 * 64];
    __shared__ __align__(16) __bf16 Vc[64 * 32];
    __shared__ __align__(16) __bf16 Pt[4][16 * 32];

    const int tid  = threadIdx.x;
    const int wave = tid >> 6;
    const int m16  = tid & 15;
    const int quad = (tid & 63) >> 4;
    const int qt = blockIdx.x, bh = blockIdx.y, split = blockIdx.z;
    const int b = bh / H_;
    const int qblk  = qt * 64;
    const int qbase = qblk + wave * 16;

    const float dist = (float)dist_p[0];
    const float md   = (float)min_dist_p[0];
    const float* yt = y_t + (size_t)b * TY_;
    const float* xt = x_t + (size_t)b * TX_;

    const float xtmin = xt[qblk] - md;
    const float xtmax = xt[qblk + 63] - md;
    int lo = 0, hi = TY_;
    while (lo < hi) { int mid = (lo + hi) >> 1; if (yt[mid] + dist < xtmin) lo = mid + 1; else hi = mid; }
    const int klo = lo;
    lo = 0; hi = TY_;
    while (lo < hi) { int mid = (lo + hi) >> 1; if (yt[mid] <= xtmax) lo = mid + 1; else hi = mid; }
    const int khi = lo - 1;
    const int len = khi - klo + 1;

    int k0 = klo, k1 = klo;
    if (len > 0) {
        const int cnt = (len + NSPLIT - 1) / NSPLIT;
        k0 = klo + split * cnt;
        k1 = min(k0 + cnt, klo + len);
    }

    float xtq[4];
#pragma unroll
    for (int r = 0; r < 4; r++)
        xtq[r] = xt[qbase + quad * 4 + r] - md;

    const __bf16* qp = Qb + ((size_t)bh * TX_ + qbase + m16) * 64;
    const bf16x8 aq0 = *(const bf16x8*)(qp + quad * 8);
    const bf16x8 aq1 = *(const bf16x8*)(qp + 32 + quad * 8);

    float l[4];
    floatx4 o[4];
#pragma unroll
    for (int r = 0; r < 4; r++) l[r] = 0.f;
#pragma unroll
    for (int t = 0; t < 4; t++) o[t] = (floatx4){0.f, 0.f, 0.f, 0.f};

    for (int kc = k0; kc < k1; kc += 32) {
        const float yt0 = yt[min(kc + m16, TY_ - 1)];
        const float yt1 = yt[min(kc + 16 + m16, TY_ - 1)];

        __syncthreads();
        {
            const int krow = tid >> 3;
            const int kg = min(kc + krow, TY_ - 1);
            async_copy16(Kb + ((size_t)bh * TY_ + kg) * 64 + (tid & 7) * 8,
                         (char*)Kc + tid * 16);
            const int d = tid >> 2;
            const int kv = min(kc + (tid & 3) * 8, TY_ - 8);
            async_copy16(Vt + ((size_t)bh * 64 + d) * TY_ + kv,
                         (char*)Vc + tid * 16);
        }
        __syncthreads();

        const bf16x8 bk0h0 = *(const bf16x8*)(Kc + m16 * 64 + quad * 8);
        const bf16x8 bk1h0 = *(const bf16x8*)(Kc + m16 * 64 + 32 + quad * 8);
        const bf16x8 bk0h1 = *(const bf16x8*)(Kc + (16 + m16) * 64 + quad * 8);
        const bf16x8 bk1h1 = *(const bf16x8*)(Kc + (16 + m16) * 64 + 32 + quad * 8);
        floatx4 s0 = (floatx4){0.f, 0.f, 0.f, 0.f};
        floatx4 s1 = (floatx4){0.f, 0.f, 0.f, 0.f};
        s0 = __builtin_amdgcn_mfma_f32_16x16x32_bf16(aq0, bk0h0, s0, 0, 0, 0);
        s0 = __builtin_amdgcn_mfma_f32_16x16x32_bf16(aq1, bk1h0, s0, 0, 0, 0);
        s1 = __builtin_amdgcn_mfma_f32_16x16x32_bf16(aq0, bk0h1, s1, 0, 0, 0);
        s1 = __builtin_amdgcn_mfma_f32_16x16x32_bf16(aq1, bk1h1, s1, 0, 0, 0);

        const int kg0 = kc + m16;
        const int kg1 = kc + 16 + m16;
        __bf16* pt = Pt[wave];
#pragma unroll
        for (int r = 0; r < 4; r++) {
            const bool v0 = (kg0 < k1) && (xtq[r] >= yt0) && (xtq[r] <= yt0 + dist);
            const bool v1 = (kg1 < k1) && (xtq[r] >= yt1) && (xtq[r] <= yt1 + dist);
            const float p0 = v0 ? (float)(__bf16)__expf(s0[r]) : 0.f;
            const float p1 = v1 ? (float)(__bf16)__expf(s1[r]) : 0.f;
            l[r] += p0 + p1;
            pt[(quad * 4 + r) * 32 + m16]      = (__bf16)p0;
            pt[(quad * 4 + r) * 32 + 16 + m16] = (__bf16)p1;
        }
        const bf16x8 ap = *(const bf16x8*)(pt + m16 * 32 + quad * 8);
#pragma unroll
        for (int t = 0; t < 4; t++) {
            const bf16x8 bv = *(const bf16x8*)(Vc + (t * 16 + m16) * 32 + quad * 8);
            o[t] = __builtin_amdgcn_mfma_f32_16x16x32_bf16(ap, bv, o[t], 0, 0, 0);
        }
    }

#pragma unroll
    for (int r = 0; r < 4; r++) {
#pragma unroll
        for (int w = 1; w < 16; w <<= 1)
            l[r] += __shfl_xor(l[r], w);
    }

#pragma unroll
    for (int t = 0; t < 4; t++)
#pragma unroll
        for (int r = 0; r < 4; r++) {
            const size_t gr = (size_t)bh * TX_ + qbase + quad * 4 + r;
            pacc[((size_t)split * R_ + gr) * 64 + t * 16 + m16] = o[t][r];
        }
    if (m16 == 0) {
#pragma unroll
        for (int r = 0; r < 4; r++) {
            const size_t gr = (size_t)bh * TX_ + qbase + quad * 4 + r;
            pml[(size_t)split * R_ + gr] = l[r];
        }
    }
}

// ---------------------------------------------------------------------------
// Combine NSPLIT partials -> Ob bf16 (B,TX,C)
// ---------------------------------------------------------------------------
__global__ __launch_bounds__(256)
void combine_kernel(const float* __restrict__ pacc,
                    const float* __restrict__ pml,
                    __bf16* __restrict__ O)
{
    const int d   = threadIdx.x;
    const int sub = threadIdx.y;
    const size_t r = (size_t)blockIdx.x * 4 + sub;
    const int bh  = (int)(r / TX_);
    const int txg = (int)(r % TX_);
    const int b = bh / H_, h = bh % H_;

    float L = 0.f, val = 0.f;
#pragma unroll
    for (int s = 0; s < NSPLIT; s++) {
        L   += pml[(size_t)s * R_ + r];
        val += pacc[((size_t)s * R_ + r) * 64 + d];
    }
    const float o = (L > 0.f) ? val / L : 0.f;
    O[(size_t)(b * TX_ + txg) * C_ + h * D_ + d] = (__bf16)o;
}

// ---------------------------------------------------------------------------
// proj GEMM: out(M,768 f32) = A(M,768 bf16) @ Bt(768,768 bf16)^T
// 128x128 tile. Pipelined: 24 chunks of 32-k, 3 rotating 16KB buffers (48KB),
// counted vmcnt(4). Only 96 blocks -> all resident, single batch already.
// ---------------------------------------------------------------------------
__global__ __launch_bounds__(256)
void gemm_proj(const __bf16* __restrict__ A,
               const __bf16* __restrict__ Bt,
               float* __restrict__ out0)
{
    __shared__ __align__(16) float smem_f[12288];   // 49152 B
    __bf16* smem_b = (__bf16*)smem_f;

    const int tid  = threadIdx.x;
    const int wave = tid >> 6;
    const int lane = tid & 63;
    const int m16  = lane & 15;
    const int quad = lane >> 4;
    const int wm   = wave >> 1;
    const int wn   = wave & 1;
    const int row0 = blockIdx.y * 128;
    const int n0   = blockIdx.x * 128;

    floatx4 acc[4][4];
#pragma unroll
    for (int i = 0; i < 4; i++)
#pragma unroll
        for (int j = 0; j < 4; j++) acc[i][j] = (floatx4){0.f, 0.f, 0.f, 0.f};

    int srow[4], scol[4];
#pragma unroll
    for (int j = 0; j < 4; j++) {
        int e = j * 2048 + wave * 512 + lane * 8;
        int e2 = e & 4095;
        srow[j] = e2 >> 5;
        scol[j] = e2 & 31;
    }

    auto stage = [&](int chunk, int buf) {
        const int kk = chunk * 32;
#pragma unroll
        for (int j = 0; j < 4; j++) {
            const __bf16* src = (j < 2)
                ? A  + (size_t)(row0 + srow[j]) * C_ + (kk + scol[j])
                : Bt + (size_t)(n0   + srow[j]) * C_ + (kk + scol[j]);
            async_copy16(src, (char*)smem_f + buf * 16384 + j * 4096 + wave * 1024);
        }
    };

    stage(0, 0);
    stage(1, 1);

    int cur = 0;
    for (int t = 0; t < 24; ++t) {
        if (t < 23) asm volatile("s_waitcnt vmcnt(4)" ::: "memory");
        else        asm volatile("s_waitcnt vmcnt(0)" ::: "memory");
        __builtin_amdgcn_s_barrier();
        asm volatile("" ::: "memory");

        if (t + 2 < 24) {
            int nb = cur + 2; if (nb >= 3) nb -= 3;
            stage(t + 2, nb);
        }

        const __bf16* As = smem_b + cur * 8192;
        const __bf16* Bs = As + 4096;
        bf16x8 af[4], bfr[4];
#pragma unroll
        for (int i = 0; i < 4; i++)
            af[i] = *(const bf16x8*)(As + (size_t)(wm * 64 + i * 16 + m16) * 32 + quad * 8);
#pragma unroll
        for (int j = 0; j < 4; j++)
            bfr[j] = *(const bf16x8*)(Bs + (size_t)(wn * 64 + j * 16 + m16) * 32 + quad * 8);
#pragma unroll
        for (int i = 0; i < 4; i++)
#pragma unroll
            for (int j = 0; j < 4; j++)
                acc[i][j] = __builtin_amdgcn_mfma_f32_16x16x32_bf16(af[i], bfr[j], acc[i][j], 0, 0, 0);

        cur = (cur == 2) ? 0 : cur + 1;
    }

    const int STR = 132;
    float* fs = smem_f;
#pragma unroll
    for (int i = 0; i < 4; i++) {
        __syncthreads();
#pragma unroll
        for (int j = 0; j < 4; j++) {
            const int col_l = wn * 64 + j * 16 + m16;
#pragma unroll
            for (int r = 0; r < 4; r++)
                fs[(wm * 16 + quad * 4 + r) * STR + col_l] = acc[i][j][r];
        }
        __syncthreads();
        const int r32 = tid >> 3;
        const int lc  = (tid & 7) * 4;
        const int row = row0 + (r32 >> 4) * 64 + i * 16 + (r32 & 15);
        float* gp = out0 + (size_t)row * C_ + n0;
#pragma unroll
        for (int c2 = 0; c2 < 4; c2++) {
            float4 v4 = *(const float4*)&fs[r32 * STR + c2 * 32 + lc];
            *(float4*)(gp + c2 * 32 + lc) = v4;
        }
    }
}

// ---------------------------------------------------------------------------
extern "C" void kernel_launch(void* const* d_in, const int* in_sizes, int n_in,
                              void* d_out, int out_size, void* d_ws, size_t ws_size,
                              hipStream_t stream)
{
    const float* x        = (const float*)d_in[0];
    const float* x_t      = (const float*)d_in[1];
    const float* y        = (const float*)d_in[2];
    const float* y_t      = (const float*)d_in[3];
    const int*   dist     = (const int*)d_in[4];
    const int*   min_dist = (const int*)d_in[5];
    const float* Wq       = (const float*)d_in[6];
    const float* Wkv      = (const float*)d_in[7];
    const float* Wproj    = (const float*)d_in[8];
    const float* inv_freq = (const float*)d_in[9];
    float* out = (float*)d_out;

    const size_t QN = (size_t)B_ * TX_ * C_;
    const size_t KN = (size_t)B_ * TY_ * C_;

    float* ws = (float*)d_ws;
    float* pacc = ws; ws += (size_t)NSPLIT * R_ * 64;
    float* pml  = ws; ws += (size_t)NSPLIT * R_;
    __bf16* bws = (__bf16*)ws;
    __bf16* xb    = bws; bws += QN;
    __bf16* yb    = bws; bws += KN;
    __bf16* Wqt   = bws; bws += (size_t)C_ * C_;
    __bf16* Wkvt  = bws; bws += (size_t)C_ * 2 * C_;
    __bf16* Wprt  = bws; bws += (size_t)C_ * C_;
    __bf16* Ob    = bws; bws += QN;
    __bf16* Qbh   = bws; bws += QN;          // [bh][TX][64]
    __bf16* Kbh   = bws; bws += KN;          // [bh][TY][64]
    __bf16* Vtb   = bws; bws += KN + 128;    // [bh][64][TY]

    prep<<<dim3(2304 + 3840), dim3(256), 0, stream>>>(
        x, xb, y, yb, Wq, Wqt, Wkv, Wkvt, Wproj, Wprt);

    gemm_qkv<<<dim3(864), dim3(256), 0, stream>>>(
        xb, Wqt, yb, Wkvt, Qbh, Kbh, Vtb, x_t, y_t, inv_freq);

    attn_mfma<<<dim3(TX_ / 64, B_ * H_, NSPLIT), dim3(256), 0, stream>>>(
        Qbh, Kbh, Vtb, x_t, y_t, dist, min_dist, pacc, pml);

    combine_kernel<<<dim3((unsigned)(R_ / 4)), dim3(64, 4), 0, stream>>>(
        pacc, pml, Ob);

    gemm_proj<<<dim3(C_ / 128, (B_ * TX_) / 128), dim3(256), 0, stream>>>(
        Ob, Wprt, out);
}

// Round 4
// 186.181 us; speedup vs baseline: 1.0523x; 1.0471x over previous
//
#include <hip/hip_runtime.h>
#include <hip/hip_bf16.h>
#include <math.h>

#define B_ 2
#define TX_ 1024
#define TY_ 4096
#define C_ 768
#define H_ 12
#define D_ 64
#define NSPLIT 2
#define R_ (B_ * H_ * TX_)

typedef __bf16 bf16x8 __attribute__((ext_vector_type(8)));
typedef float floatx4 __attribute__((ext_vector_type(4)));

__device__ __forceinline__ void async_copy16(const void* g, void* l) {
    __builtin_amdgcn_global_load_lds(
        (const __attribute__((address_space(1))) unsigned int*)g,
        (__attribute__((address_space(3))) unsigned int*)l,
        16, 0, 0);
}

__device__ __forceinline__ bf16x8 cvt8(const float* s) {
    bf16x8 r;
#pragma unroll
    for (int i = 0; i < 8; i++) r[i] = (__bf16)s[i];
    return r;
}

// ---------------------------------------------------------------------------
// prep: ONE launch: (a) 3 weight transposes W(768xN f32)->Wt(Nx768 bf16),
// (b) x,y f32->bf16 conversion (8 elems/thread).
// ---------------------------------------------------------------------------
__global__ __launch_bounds__(256)
void prep(const float* __restrict__ x,  __bf16* __restrict__ xb,
          const float* __restrict__ y,  __bf16* __restrict__ yb,
          const float* __restrict__ Wq, __bf16* __restrict__ Wqt,
          const float* __restrict__ Wkv,__bf16* __restrict__ Wkvt,
          const float* __restrict__ Wpr,__bf16* __restrict__ Wprt)
{
    __shared__ float tile[32][33];
    const int bid = blockIdx.x;
    if (bid >= 2304) {
        const int cb = bid - 2304;
        const float* src; __bf16* dst; size_t base;
        if (cb < 768) { src = x; dst = xb; base = (size_t)cb * 2048; }
        else          { src = y; dst = yb; base = (size_t)(cb - 768) * 2048; }
        const size_t i = base + threadIdx.x * 8;
        float4 v0 = *(const float4*)(src + i);
        float4 v1 = *(const float4*)(src + i + 4);
        bf16x8 p;
        p[0] = (__bf16)v0.x; p[1] = (__bf16)v0.y; p[2] = (__bf16)v0.z; p[3] = (__bf16)v0.w;
        p[4] = (__bf16)v1.x; p[5] = (__bf16)v1.y; p[6] = (__bf16)v1.z; p[7] = (__bf16)v1.w;
        *(bf16x8*)(dst + i) = p;
        return;
    }
    const int bxr = bid % 96;
    const int byr = bid / 96;
    const float* W; __bf16* Wt; int N, nb; float scale = 1.0f;
    if (bxr < 24)      { W = Wq;  Wt = Wqt;  N = C_;     nb = bxr;      scale = 0.125f; }
    else if (bxr < 72) { W = Wkv; Wt = Wkvt; N = 2 * C_; nb = bxr - 24; }
    else               { W = Wpr; Wt = Wprt; N = C_;     nb = bxr - 72; }
    const int bx = nb * 32;
    const int by = byr * 32;
    const int tx = threadIdx.x & 31, ty = threadIdx.x >> 5;
#pragma unroll
    for (int i = 0; i < 4; i++)
        tile[ty + i * 8][tx] = W[(size_t)(by + ty + i * 8) * N + bx + tx];
    __syncthreads();
#pragma unroll
    for (int i = 0; i < 4; i++)
        Wt[(size_t)(bx + ty + i * 8) * C_ + by + tx] =
            (__bf16)(tile[tx][ty + i * 8] * scale);
}

// ---------------------------------------------------------------------------
// Fused Q + KV MFMA GEMM, 1D grid 1728 blocks (192 Q tiles first, 1536 KV).
// ROUND-1 PROVEN STRUCTURE (54.5us): 64x128 tile, 24 chunks of 32-k, 3
// rotating 12KB LDS buffers (36KB), one barrier per chunk, counted
// s_waitcnt vmcnt(3) -- next chunk's 3 loads stay in flight across the
// barrier. NEW vs r1: XCD-bijective swizzle (1728 = 8*216) -- r3 proved it
// cuts FETCH_SIZE 2.6x (65->25MB) via L2 panel sharing.
// Wave layout: 2x2, each wave 32 rows x 64 cols -> acc[2][4].
//   bid <  192: Q : rope -> Qbh [bh][TX][64]
//   bid >= 192: KV: n0<C_ rope -> Kbh [bh][TY][64]; n0>=C_ -> Vtb [bh][64][TY]
// ---------------------------------------------------------------------------
__global__ __launch_bounds__(256)
void gemm_qkv(const __bf16* __restrict__ xb, const __bf16* __restrict__ Wqt,
              const __bf16* __restrict__ yb, const __bf16* __restrict__ Wkvt,
              __bf16* __restrict__ Qbh, __bf16* __restrict__ Kbh,
              __bf16* __restrict__ Vtb,
              const float* __restrict__ x_t, const float* __restrict__ y_t,
              const float* __restrict__ inv_freq)
{
    // bijective XCD swizzle: 1728 = 8 * 216
    const int bid = (blockIdx.x & 7) * 216 + (blockIdx.x >> 3);
    const bool isQ = (bid < 192);
    const __bf16* A; const __bf16* Bt; const float* t_arr;
    int row0, n0, T, TSH;
    if (isQ) {
        A = xb; Bt = Wqt; t_arr = x_t;
        row0 = (bid / 6) * 64; n0 = (bid % 6) * 128; T = TX_; TSH = 10;
    } else {
        const int r = bid - 192;
        A = yb; Bt = Wkvt; t_arr = y_t;
        row0 = (r / 12) * 64; n0 = (r % 12) * 128; T = TY_; TSH = 12;
    }
    const bool isV = (!isQ) && (n0 >= C_);

    // 3 pipeline buffers x 12KB (4KB A + 8KB B) = 36864 B
    __shared__ __align__(16) float smem_f[9216];
    __bf16* smem_b = (__bf16*)smem_f;

    const int tid  = threadIdx.x;
    const int wave = tid >> 6;
    const int lane = tid & 63;
    const int m16  = lane & 15;
    const int quad = lane >> 4;
    const int wm   = wave >> 1;
    const int wn   = wave & 1;

    floatx4 acc[2][4];
#pragma unroll
    for (int i = 0; i < 2; i++)
#pragma unroll
        for (int j = 0; j < 4; j++) acc[i][j] = (floatx4){0.f, 0.f, 0.f, 0.f};

    // A staging: 64x32 bf16 = 4096 B = 256 lanes x 16 B (one issue)
    const int eA = wave * 512 + lane * 8;
    const int srA = eA >> 5, scA = eA & 31;
    // B staging: 128x32 bf16 = 8192 B = two issues j in {0,1}
    int srB[2], scB[2];
#pragma unroll
    for (int j = 0; j < 2; j++) {
        const int e = j * 2048 + wave * 512 + lane * 8;
        srB[j] = e >> 5; scB[j] = e & 31;
    }

    auto stage = [&](int chunk, int buf) {
        const int kk = chunk * 32;
        async_copy16(A + (size_t)(row0 + srA) * C_ + (kk + scA),
                     (char*)smem_f + buf * 12288 + wave * 1024);
#pragma unroll
        for (int j = 0; j < 2; j++)
            async_copy16(Bt + (size_t)(n0 + srB[j]) * C_ + (kk + scB[j]),
                         (char*)smem_f + buf * 12288 + 4096 + j * 4096 + wave * 1024);
    };

    // prologue: chunks 0,1 in flight
    stage(0, 0);
    stage(1, 1);

    int cur = 0;
    for (int t = 0; t < 24; ++t) {
        // wait for chunk t (own 3 loads); chunk t+1's 3 may stay in flight
        if (t < 23) asm volatile("s_waitcnt vmcnt(3)" ::: "memory");
        else        asm volatile("s_waitcnt vmcnt(0)" ::: "memory");
        __builtin_amdgcn_s_barrier();
        asm volatile("" ::: "memory");

        if (t + 2 < 24) {
            int nb = cur + 2; if (nb >= 3) nb -= 3;
            stage(t + 2, nb);   // buffer last read at iter t-1, before this barrier
        }

        const __bf16* As = smem_b + cur * 6144;
        const __bf16* Bs = As + 2048;
        bf16x8 af[2], bfr[4];
#pragma unroll
        for (int i = 0; i < 2; i++)
            af[i] = *(const bf16x8*)(As + (size_t)(wm * 32 + i * 16 + m16) * 32 + quad * 8);
#pragma unroll
        for (int j = 0; j < 4; j++)
            bfr[j] = *(const bf16x8*)(Bs + (size_t)(wn * 64 + j * 16 + m16) * 32 + quad * 8);
#pragma unroll
        for (int i = 0; i < 2; i++)
#pragma unroll
            for (int j = 0; j < 4; j++)
                acc[i][j] = __builtin_amdgcn_mfma_f32_16x16x32_bf16(af[i], bfr[j], acc[i][j], 0, 0, 0);

        cur = (cur == 2) ? 0 : cur + 1;
    }

    // ---- epilogue (LDS-staged, full-line stores), i in {0,1}: 32 rows each
    const int STR = 132;
    float* fs = smem_f;

#pragma unroll
    for (int i = 0; i < 2; i++) {
        __syncthreads();
#pragma unroll
        for (int j = 0; j < 4; j++) {
            const int col_l = wn * 64 + j * 16 + m16;
#pragma unroll
            for (int r = 0; r < 4; r++) {
                const int row_l = quad * 4 + r;
                float v = acc[i][j][r];
                if (!isV) {
                    const float vp = __shfl_xor(v, 1);
                    const int row = row0 + wm * 32 + i * 16 + row_l;
                    const int cc = (n0 + col_l) & (D_ - 1);
                    const float fr = t_arr[row] * inv_freq[cc >> 1];
                    const float sn = __sinf(fr), cs = __cosf(fr);
                    v = (m16 & 1) ? (v * cs + vp * sn) : (v * cs - vp * sn);
                }
                fs[(wm * 16 + row_l) * STR + col_l] = v;
            }
        }
        __syncthreads();

        if (!isV) {
            __bf16* outb = isQ ? Qbh : Kbh;
            const int r32 = tid >> 3;                 // 0..31
            const int lane8 = tid & 7;
            const int grow = row0 + (r32 >> 4) * 32 + i * 16 + (r32 & 15);
            const int bb = grow >> TSH;
            const int rk = grow & (T - 1);
            const int h  = (n0 >> 6) + (lane8 >> 2);
            const int d0 = (lane8 & 3) * 16;
            __bf16* gp = outb + ((size_t)(bb * H_ + h) * T + rk) * 64 + d0;
            const float* sp = &fs[r32 * STR + lane8 * 16];
            *(bf16x8*)gp       = cvt8(sp);
            *(bf16x8*)(gp + 8) = cvt8(sp + 8);
        } else {
            const int dcol = tid >> 1;                // 0..127
            const int g16  = tid & 1;                 // 16-row group
            const int h  = ((n0 - C_) >> 6) + (dcol >> 6);
            const int dd = dcol & 63;
            const int kbase = row0 + g16 * 32 + i * 16;
            const int bb  = kbase >> 12;
            const int kin = kbase & (TY_ - 1);
            float tmp[16];
#pragma unroll
            for (int jj = 0; jj < 16; jj++)
                tmp[jj] = fs[(g16 * 16 + jj) * STR + dcol];
            __bf16* gp = Vtb + ((size_t)(bb * H_ + h) * 64 + dd) * TY_ + kin;
            *(bf16x8*)gp       = cvt8(tmp);
            *(bf16x8*)(gp + 8) = cvt8(tmp + 8);
        }
    }
}

// ---------------------------------------------------------------------------
// MFMA flash attention (round-8 proven version): LDS-staged 32-k chunks,
// no-max softmax, block = 4 waves = 64 q rows, NSPLIT k-splits.
// ---------------------------------------------------------------------------
__global__ __launch_bounds__(256)
void attn_mfma(const __bf16* __restrict__ Qb,
               const __bf16* __restrict__ Kb,
               const __bf16* __restrict__ Vt,
               const float* __restrict__ x_t,
               const float* __restrict__ y_t,
               const int* __restrict__ dist_p,
               const int* __restrict__ min_dist_p,
               float* __restrict__ pacc,
               float* __restrict__ pml)
{
    __shared__ __align__(16) __bf16 Kc[32 * 64];
    __shared__ __align__(16) __bf16 Vc[64 * 32];
    __shared__ __align__(16) __bf16 Pt[4][16 * 32];

    const int tid  = threadIdx.x;
    const int wave = tid >> 6;
    const int m16  = tid & 15;
    const int quad = (tid & 63) >> 4;
    const int qt = blockIdx.x, bh = blockIdx.y, split = blockIdx.z;
    const int b = bh / H_;
    const int qblk  = qt * 64;
    const int qbase = qblk + wave * 16;

    const float dist = (float)dist_p[0];
    const float md   = (float)min_dist_p[0];
    const float* yt = y_t + (size_t)b * TY_;
    const float* xt = x_t + (size_t)b * TX_;

    const float xtmin = xt[qblk] - md;
    const float xtmax = xt[qblk + 63] - md;
    int lo = 0, hi = TY_;
    while (lo < hi) { int mid = (lo + hi) >> 1; if (yt[mid] + dist < xtmin) lo = mid + 1; else hi = mid; }
    const int klo = lo;
    lo = 0; hi = TY_;
    while (lo < hi) { int mid = (lo + hi) >> 1; if (yt[mid] <= xtmax) lo = mid + 1; else hi = mid; }
    const int khi = lo - 1;
    const int len = khi - klo + 1;

    int k0 = klo, k1 = klo;
    if (len > 0) {
        const int cnt = (len + NSPLIT - 1) / NSPLIT;
        k0 = klo + split * cnt;
        k1 = min(k0 + cnt, klo + len);
    }

    float xtq[4];
#pragma unroll
    for (int r = 0; r < 4; r++)
        xtq[r] = xt[qbase + quad * 4 + r] - md;

    const __bf16* qp = Qb + ((size_t)bh * TX_ + qbase + m16) * 64;
    const bf16x8 aq0 = *(const bf16x8*)(qp + quad * 8);
    const bf16x8 aq1 = *(const bf16x8*)(qp + 32 + quad * 8);

    float l[4];
    floatx4 o[4];
#pragma unroll
    for (int r = 0; r < 4; r++) l[r] = 0.f;
#pragma unroll
    for (int t = 0; t < 4; t++) o[t] = (floatx4){0.f, 0.f, 0.f, 0.f};

    for (int kc = k0; kc < k1; kc += 32) {
        const float yt0 = yt[min(kc + m16, TY_ - 1)];
        const float yt1 = yt[min(kc + 16 + m16, TY_ - 1)];

        __syncthreads();
        {
            const int krow = tid >> 3;
            const int kg = min(kc + krow, TY_ - 1);
            async_copy16(Kb + ((size_t)bh * TY_ + kg) * 64 + (tid & 7) * 8,
                         (char*)Kc + tid * 16);
            const int d = tid >> 2;
            const int kv = min(kc + (tid & 3) * 8, TY_ - 8);
            async_copy16(Vt + ((size_t)bh * 64 + d) * TY_ + kv,
                         (char*)Vc + tid * 16);
        }
        __syncthreads();

        const bf16x8 bk0h0 = *(const bf16x8*)(Kc + m16 * 64 + quad * 8);
        const bf16x8 bk1h0 = *(const bf16x8*)(Kc + m16 * 64 + 32 + quad * 8);
        const bf16x8 bk0h1 = *(const bf16x8*)(Kc + (16 + m16) * 64 + quad * 8);
        const bf16x8 bk1h1 = *(const bf16x8*)(Kc + (16 + m16) * 64 + 32 + quad * 8);
        floatx4 s0 = (floatx4){0.f, 0.f, 0.f, 0.f};
        floatx4 s1 = (floatx4){0.f, 0.f, 0.f, 0.f};
        s0 = __builtin_amdgcn_mfma_f32_16x16x32_bf16(aq0, bk0h0, s0, 0, 0, 0);
        s0 = __builtin_amdgcn_mfma_f32_16x16x32_bf16(aq1, bk1h0, s0, 0, 0, 0);
        s1 = __builtin_amdgcn_mfma_f32_16x16x32_bf16(aq0, bk0h1, s1, 0, 0, 0);
        s1 = __builtin_amdgcn_mfma_f32_16x16x32_bf16(aq1, bk1h1, s1, 0, 0, 0);

        const int kg0 = kc + m16;
        const int kg1 = kc + 16 + m16;
        __bf16* pt = Pt[wave];
#pragma unroll
        for (int r = 0; r < 4; r++) {
            const bool v0 = (kg0 < k1) && (xtq[r] >= yt0) && (xtq[r] <= yt0 + dist);
            const bool v1 = (kg1 < k1) && (xtq[r] >= yt1) && (xtq[r] <= yt1 + dist);
            const float p0 = v0 ? (float)(__bf16)__expf(s0[r]) : 0.f;
            const float p1 = v1 ? (float)(__bf16)__expf(s1[r]) : 0.f;
            l[r] += p0 + p1;
            pt[(quad * 4 + r) * 32 + m16]      = (__bf16)p0;
            pt[(quad * 4 + r) * 32 + 16 + m16] = (__bf16)p1;
        }
        const bf16x8 ap = *(const bf16x8*)(pt + m16 * 32 + quad * 8);
#pragma unroll
        for (int t = 0; t < 4; t++) {
            const bf16x8 bv = *(const bf16x8*)(Vc + (t * 16 + m16) * 32 + quad * 8);
            o[t] = __builtin_amdgcn_mfma_f32_16x16x32_bf16(ap, bv, o[t], 0, 0, 0);
        }
    }

#pragma unroll
    for (int r = 0; r < 4; r++) {
#pragma unroll
        for (int w = 1; w < 16; w <<= 1)
            l[r] += __shfl_xor(l[r], w);
    }

#pragma unroll
    for (int t = 0; t < 4; t++)
#pragma unroll
        for (int r = 0; r < 4; r++) {
            const size_t gr = (size_t)bh * TX_ + qbase + quad * 4 + r;
            pacc[((size_t)split * R_ + gr) * 64 + t * 16 + m16] = o[t][r];
        }
    if (m16 == 0) {
#pragma unroll
        for (int r = 0; r < 4; r++) {
            const size_t gr = (size_t)bh * TX_ + qbase + quad * 4 + r;
            pml[(size_t)split * R_ + gr] = l[r];
        }
    }
}

// ---------------------------------------------------------------------------
// Combine NSPLIT partials -> Ob bf16 (B,TX,C)
// ---------------------------------------------------------------------------
__global__ __launch_bounds__(256)
void combine_kernel(const float* __restrict__ pacc,
                    const float* __restrict__ pml,
                    __bf16* __restrict__ O)
{
    const int d   = threadIdx.x;
    const int sub = threadIdx.y;
    const size_t r = (size_t)blockIdx.x * 4 + sub;
    const int bh  = (int)(r / TX_);
    const int txg = (int)(r % TX_);
    const int b = bh / H_, h = bh % H_;

    float L = 0.f, val = 0.f;
#pragma unroll
    for (int s = 0; s < NSPLIT; s++) {
        L   += pml[(size_t)s * R_ + r];
        val += pacc[((size_t)s * R_ + r) * 64 + d];
    }
    const float o = (L > 0.f) ? val / L : 0.f;
    O[(size_t)(b * TX_ + txg) * C_ + h * D_ + d] = (__bf16)o;
}

// ---------------------------------------------------------------------------
// proj GEMM: out(M,768 f32) = A(M,768 bf16) @ Bt(768,768 bf16)^T
// 128x128 tile. Pipelined: 24 chunks of 32-k, 3 rotating 16KB buffers (48KB),
// counted vmcnt(4). Only 96 blocks -> all resident, single batch already.
// ---------------------------------------------------------------------------
__global__ __launch_bounds__(256)
void gemm_proj(const __bf16* __restrict__ A,
               const __bf16* __restrict__ Bt,
               float* __restrict__ out0)
{
    __shared__ __align__(16) float smem_f[12288];   // 49152 B
    __bf16* smem_b = (__bf16*)smem_f;

    const int tid  = threadIdx.x;
    const int wave = tid >> 6;
    const int lane = tid & 63;
    const int m16  = lane & 15;
    const int quad = lane >> 4;
    const int wm   = wave >> 1;
    const int wn   = wave & 1;
    const int row0 = blockIdx.y * 128;
    const int n0   = blockIdx.x * 128;

    floatx4 acc[4][4];
#pragma unroll
    for (int i = 0; i < 4; i++)
#pragma unroll
        for (int j = 0; j < 4; j++) acc[i][j] = (floatx4){0.f, 0.f, 0.f, 0.f};

    int srow[4], scol[4];
#pragma unroll
    for (int j = 0; j < 4; j++) {
        int e = j * 2048 + wave * 512 + lane * 8;
        int e2 = e & 4095;
        srow[j] = e2 >> 5;
        scol[j] = e2 & 31;
    }

    auto stage = [&](int chunk, int buf) {
        const int kk = chunk * 32;
#pragma unroll
        for (int j = 0; j < 4; j++) {
            const __bf16* src = (j < 2)
                ? A  + (size_t)(row0 + srow[j]) * C_ + (kk + scol[j])
                : Bt + (size_t)(n0   + srow[j]) * C_ + (kk + scol[j]);
            async_copy16(src, (char*)smem_f + buf * 16384 + j * 4096 + wave * 1024);
        }
    };

    stage(0, 0);
    stage(1, 1);

    int cur = 0;
    for (int t = 0; t < 24; ++t) {
        if (t < 23) asm volatile("s_waitcnt vmcnt(4)" ::: "memory");
        else        asm volatile("s_waitcnt vmcnt(0)" ::: "memory");
        __builtin_amdgcn_s_barrier();
        asm volatile("" ::: "memory");

        if (t + 2 < 24) {
            int nb = cur + 2; if (nb >= 3) nb -= 3;
            stage(t + 2, nb);
        }

        const __bf16* As = smem_b + cur * 8192;
        const __bf16* Bs = As + 4096;
        bf16x8 af[4], bfr[4];
#pragma unroll
        for (int i = 0; i < 4; i++)
            af[i] = *(const bf16x8*)(As + (size_t)(wm * 64 + i * 16 + m16) * 32 + quad * 8);
#pragma unroll
        for (int j = 0; j < 4; j++)
            bfr[j] = *(const bf16x8*)(Bs + (size_t)(wn * 64 + j * 16 + m16) * 32 + quad * 8);
#pragma unroll
        for (int i = 0; i < 4; i++)
#pragma unroll
            for (int j = 0; j < 4; j++)
                acc[i][j] = __builtin_amdgcn_mfma_f32_16x16x32_bf16(af[i], bfr[j], acc[i][j], 0, 0, 0);

        cur = (cur == 2) ? 0 : cur + 1;
    }

    const int STR = 132;
    float* fs = smem_f;
#pragma unroll
    for (int i = 0; i < 4; i++) {
        __syncthreads();
#pragma unroll
        for (int j = 0; j < 4; j++) {
            const int col_l = wn * 64 + j * 16 + m16;
#pragma unroll
            for (int r = 0; r < 4; r++)
                fs[(wm * 16 + quad * 4 + r) * STR + col_l] = acc[i][j][r];
        }
        __syncthreads();
        const int r32 = tid >> 3;
        const int lc  = (tid & 7) * 4;
        const int row = row0 + (r32 >> 4) * 64 + i * 16 + (r32 & 15);
        float* gp = out0 + (size_t)row * C_ + n0;
#pragma unroll
        for (int c2 = 0; c2 < 4; c2++) {
            float4 v4 = *(const float4*)&fs[r32 * STR + c2 * 32 + lc];
            *(float4*)(gp + c2 * 32 + lc) = v4;
        }
    }
}

// ---------------------------------------------------------------------------
extern "C" void kernel_launch(void* const* d_in, const int* in_sizes, int n_in,
                              void* d_out, int out_size, void* d_ws, size_t ws_size,
                              hipStream_t stream)
{
    const float* x        = (const float*)d_in[0];
    const float* x_t      = (const float*)d_in[1];
    const float* y        = (const float*)d_in[2];
    const float* y_t      = (const float*)d_in[3];
    const int*   dist     = (const int*)d_in[4];
    const int*   min_dist = (const int*)d_in[5];
    const float* Wq       = (const float*)d_in[6];
    const float* Wkv      = (const float*)d_in[7];
    const float* Wproj    = (const float*)d_in[8];
    const float* inv_freq = (const float*)d_in[9];
    float* out = (float*)d_out;

    const size_t QN = (size_t)B_ * TX_ * C_;
    const size_t KN = (size_t)B_ * TY_ * C_;

    float* ws = (float*)d_ws;
    float* pacc = ws; ws += (size_t)NSPLIT * R_ * 64;
    float* pml  = ws; ws += (size_t)NSPLIT * R_;
    __bf16* bws = (__bf16*)ws;
    __bf16* xb    = bws; bws += QN;
    __bf16* yb    = bws; bws += KN;
    __bf16* Wqt   = bws; bws += (size_t)C_ * C_;
    __bf16* Wkvt  = bws; bws += (size_t)C_ * 2 * C_;
    __bf16* Wprt  = bws; bws += (size_t)C_ * C_;
    __bf16* Ob    = bws; bws += QN;
    __bf16* Qbh   = bws; bws += QN;          // [bh][TX][64]
    __bf16* Kbh   = bws; bws += KN;          // [bh][TY][64]
    __bf16* Vtb   = bws; bws += KN + 128;    // [bh][64][TY]

    prep<<<dim3(2304 + 3840), dim3(256), 0, stream>>>(
        x, xb, y, yb, Wq, Wqt, Wkv, Wkvt, Wproj, Wprt);

    gemm_qkv<<<dim3(1728), dim3(256), 0, stream>>>(
        xb, Wqt, yb, Wkvt, Qbh, Kbh, Vtb, x_t, y_t, inv_freq);

    attn_mfma<<<dim3(TX_ / 64, B_ * H_, NSPLIT), dim3(256), 0, stream>>>(
        Qbh, Kbh, Vtb, x_t, y_t, dist, min_dist, pacc, pml);

    combine_kernel<<<dim3((unsigned)(R_ / 4)), dim3(64, 4), 0, stream>>>(
        pacc, pml, Ob);

    gemm_proj<<<dim3(C_ / 128, (B_ * TX_) / 128), dim3(256), 0, stream>>>(
        Ob, Wprt, out);
}

// Round 5
// 181.660 us; speedup vs baseline: 1.0785x; 1.0249x over previous
//
#include <hip/hip_runtime.h>
#include <hip/hip_bf16.h>
#include <math.h>

#define B_ 2
#define TX_ 1024
#define TY_ 4096
#define C_ 768
#define H_ 12
#define D_ 64
#define NSPLIT 2
#define R_ (B_ * H_ * TX_)

typedef __bf16 bf16x8 __attribute__((ext_vector_type(8)));
typedef float floatx4 __attribute__((ext_vector_type(4)));

__device__ __forceinline__ void async_copy16(const void* g, void* l) {
    __builtin_amdgcn_global_load_lds(
        (const __attribute__((address_space(1))) unsigned int*)g,
        (__attribute__((address_space(3))) unsigned int*)l,
        16, 0, 0);
}

__device__ __forceinline__ void async_copy4(const void* g, void* l) {
    __builtin_amdgcn_global_load_lds(
        (const __attribute__((address_space(1))) unsigned int*)g,
        (__attribute__((address_space(3))) unsigned int*)l,
        4, 0, 0);
}

__device__ __forceinline__ bf16x8 cvt8(const float* s) {
    bf16x8 r;
#pragma unroll
    for (int i = 0; i < 8; i++) r[i] = (__bf16)s[i];
    return r;
}

// ---------------------------------------------------------------------------
// prep: ONE launch: (a) 3 weight transposes W(768xN f32)->Wt(Nx768 bf16),
// (b) x,y f32->bf16 conversion (8 elems/thread).
// ---------------------------------------------------------------------------
__global__ __launch_bounds__(256)
void prep(const float* __restrict__ x,  __bf16* __restrict__ xb,
          const float* __restrict__ y,  __bf16* __restrict__ yb,
          const float* __restrict__ Wq, __bf16* __restrict__ Wqt,
          const float* __restrict__ Wkv,__bf16* __restrict__ Wkvt,
          const float* __restrict__ Wpr,__bf16* __restrict__ Wprt)
{
    __shared__ float tile[32][33];
    const int bid = blockIdx.x;
    if (bid >= 2304) {
        const int cb = bid - 2304;
        const float* src; __bf16* dst; size_t base;
        if (cb < 768) { src = x; dst = xb; base = (size_t)cb * 2048; }
        else          { src = y; dst = yb; base = (size_t)(cb - 768) * 2048; }
        const size_t i = base + threadIdx.x * 8;
        float4 v0 = *(const float4*)(src + i);
        float4 v1 = *(const float4*)(src + i + 4);
        bf16x8 p;
        p[0] = (__bf16)v0.x; p[1] = (__bf16)v0.y; p[2] = (__bf16)v0.z; p[3] = (__bf16)v0.w;
        p[4] = (__bf16)v1.x; p[5] = (__bf16)v1.y; p[6] = (__bf16)v1.z; p[7] = (__bf16)v1.w;
        *(bf16x8*)(dst + i) = p;
        return;
    }
    const int bxr = bid % 96;
    const int byr = bid / 96;
    const float* W; __bf16* Wt; int N, nb; float scale = 1.0f;
    if (bxr < 24)      { W = Wq;  Wt = Wqt;  N = C_;     nb = bxr;      scale = 0.125f; }
    else if (bxr < 72) { W = Wkv; Wt = Wkvt; N = 2 * C_; nb = bxr - 24; }
    else               { W = Wpr; Wt = Wprt; N = C_;     nb = bxr - 72; }
    const int bx = nb * 32;
    const int by = byr * 32;
    const int tx = threadIdx.x & 31, ty = threadIdx.x >> 5;
#pragma unroll
    for (int i = 0; i < 4; i++)
        tile[ty + i * 8][tx] = W[(size_t)(by + ty + i * 8) * N + bx + tx];
    __syncthreads();
#pragma unroll
    for (int i = 0; i < 4; i++)
        Wt[(size_t)(bx + ty + i * 8) * C_ + by + tx] =
            (__bf16)(tile[tx][ty + i * 8] * scale);
}

// ---------------------------------------------------------------------------
// Fused Q + KV MFMA GEMM (unchanged from round 4, banked at ~50.7us):
// 64x128 tile, 24 chunks of 32-k, 3 rotating 12KB LDS buffers (36KB), one
// barrier per chunk, counted vmcnt(3), XCD-bijective swizzle (1728 = 8*216).
// ---------------------------------------------------------------------------
__global__ __launch_bounds__(256)
void gemm_qkv(const __bf16* __restrict__ xb, const __bf16* __restrict__ Wqt,
              const __bf16* __restrict__ yb, const __bf16* __restrict__ Wkvt,
              __bf16* __restrict__ Qbh, __bf16* __restrict__ Kbh,
              __bf16* __restrict__ Vtb,
              const float* __restrict__ x_t, const float* __restrict__ y_t,
              const float* __restrict__ inv_freq)
{
    const int bid = (blockIdx.x & 7) * 216 + (blockIdx.x >> 3);
    const bool isQ = (bid < 192);
    const __bf16* A; const __bf16* Bt; const float* t_arr;
    int row0, n0, T, TSH;
    if (isQ) {
        A = xb; Bt = Wqt; t_arr = x_t;
        row0 = (bid / 6) * 64; n0 = (bid % 6) * 128; T = TX_; TSH = 10;
    } else {
        const int r = bid - 192;
        A = yb; Bt = Wkvt; t_arr = y_t;
        row0 = (r / 12) * 64; n0 = (r % 12) * 128; T = TY_; TSH = 12;
    }
    const bool isV = (!isQ) && (n0 >= C_);

    __shared__ __align__(16) float smem_f[9216];
    __bf16* smem_b = (__bf16*)smem_f;

    const int tid  = threadIdx.x;
    const int wave = tid >> 6;
    const int lane = tid & 63;
    const int m16  = lane & 15;
    const int quad = lane >> 4;
    const int wm   = wave >> 1;
    const int wn   = wave & 1;

    floatx4 acc[2][4];
#pragma unroll
    for (int i = 0; i < 2; i++)
#pragma unroll
        for (int j = 0; j < 4; j++) acc[i][j] = (floatx4){0.f, 0.f, 0.f, 0.f};

    const int eA = wave * 512 + lane * 8;
    const int srA = eA >> 5, scA = eA & 31;
    int srB[2], scB[2];
#pragma unroll
    for (int j = 0; j < 2; j++) {
        const int e = j * 2048 + wave * 512 + lane * 8;
        srB[j] = e >> 5; scB[j] = e & 31;
    }

    auto stage = [&](int chunk, int buf) {
        const int kk = chunk * 32;
        async_copy16(A + (size_t)(row0 + srA) * C_ + (kk + scA),
                     (char*)smem_f + buf * 12288 + wave * 1024);
#pragma unroll
        for (int j = 0; j < 2; j++)
            async_copy16(Bt + (size_t)(n0 + srB[j]) * C_ + (kk + scB[j]),
                         (char*)smem_f + buf * 12288 + 4096 + j * 4096 + wave * 1024);
    };

    stage(0, 0);
    stage(1, 1);

    int cur = 0;
    for (int t = 0; t < 24; ++t) {
        if (t < 23) asm volatile("s_waitcnt vmcnt(3)" ::: "memory");
        else        asm volatile("s_waitcnt vmcnt(0)" ::: "memory");
        __builtin_amdgcn_s_barrier();
        asm volatile("" ::: "memory");

        if (t + 2 < 24) {
            int nb = cur + 2; if (nb >= 3) nb -= 3;
            stage(t + 2, nb);
        }

        const __bf16* As = smem_b + cur * 6144;
        const __bf16* Bs = As + 2048;
        bf16x8 af[2], bfr[4];
#pragma unroll
        for (int i = 0; i < 2; i++)
            af[i] = *(const bf16x8*)(As + (size_t)(wm * 32 + i * 16 + m16) * 32 + quad * 8);
#pragma unroll
        for (int j = 0; j < 4; j++)
            bfr[j] = *(const bf16x8*)(Bs + (size_t)(wn * 64 + j * 16 + m16) * 32 + quad * 8);
#pragma unroll
        for (int i = 0; i < 2; i++)
#pragma unroll
            for (int j = 0; j < 4; j++)
                acc[i][j] = __builtin_amdgcn_mfma_f32_16x16x32_bf16(af[i], bfr[j], acc[i][j], 0, 0, 0);

        cur = (cur == 2) ? 0 : cur + 1;
    }

    const int STR = 132;
    float* fs = smem_f;

#pragma unroll
    for (int i = 0; i < 2; i++) {
        __syncthreads();
#pragma unroll
        for (int j = 0; j < 4; j++) {
            const int col_l = wn * 64 + j * 16 + m16;
#pragma unroll
            for (int r = 0; r < 4; r++) {
                const int row_l = quad * 4 + r;
                float v = acc[i][j][r];
                if (!isV) {
                    const float vp = __shfl_xor(v, 1);
                    const int row = row0 + wm * 32 + i * 16 + row_l;
                    const int cc = (n0 + col_l) & (D_ - 1);
                    const float fr = t_arr[row] * inv_freq[cc >> 1];
                    const float sn = __sinf(fr), cs = __cosf(fr);
                    v = (m16 & 1) ? (v * cs + vp * sn) : (v * cs - vp * sn);
                }
                fs[(wm * 16 + row_l) * STR + col_l] = v;
            }
        }
        __syncthreads();

        if (!isV) {
            __bf16* outb = isQ ? Qbh : Kbh;
            const int r32 = tid >> 3;
            const int lane8 = tid & 7;
            const int grow = row0 + (r32 >> 4) * 32 + i * 16 + (r32 & 15);
            const int bb = grow >> TSH;
            const int rk = grow & (T - 1);
            const int h  = (n0 >> 6) + (lane8 >> 2);
            const int d0 = (lane8 & 3) * 16;
            __bf16* gp = outb + ((size_t)(bb * H_ + h) * T + rk) * 64 + d0;
            const float* sp = &fs[r32 * STR + lane8 * 16];
            *(bf16x8*)gp       = cvt8(sp);
            *(bf16x8*)(gp + 8) = cvt8(sp + 8);
        } else {
            const int dcol = tid >> 1;
            const int g16  = tid & 1;
            const int h  = ((n0 - C_) >> 6) + (dcol >> 6);
            const int dd = dcol & 63;
            const int kbase = row0 + g16 * 32 + i * 16;
            const int bb  = kbase >> 12;
            const int kin = kbase & (TY_ - 1);
            float tmp[16];
#pragma unroll
            for (int jj = 0; jj < 16; jj++)
                tmp[jj] = fs[(g16 * 16 + jj) * STR + dcol];
            __bf16* gp = Vtb + ((size_t)(bb * H_ + h) * 64 + dd) * TY_ + kin;
            *(bf16x8*)gp       = cvt8(tmp);
            *(bf16x8*)(gp + 8) = cvt8(tmp + 8);
        }
    }
}

// ---------------------------------------------------------------------------
// MFMA flash attention, NOW PIPELINED like gemm_qkv's r1 loop: 3 rotating
// K/V/yt LDS buffers, ONE barrier per 32-k chunk (was 2 + full drain),
// counted vmcnt (never 0 mid-loop). yt values staged to LDS via 4-byte
// global_load_lds with per-lane clamped source (exact old semantics),
// removing per-chunk global loads from the critical path.
// Wave 0 issues 3 VMEM/chunk (K,V,yt), waves 1-3 issue 2 -> wave-dependent
// counted wait vmcnt(3)/vmcnt(2).
// ---------------------------------------------------------------------------
__global__ __launch_bounds__(256)
void attn_mfma(const __bf16* __restrict__ Qb,
               const __bf16* __restrict__ Kb,
               const __bf16* __restrict__ Vt,
               const float* __restrict__ x_t,
               const float* __restrict__ y_t,
               const int* __restrict__ dist_p,
               const int* __restrict__ min_dist_p,
               float* __restrict__ pacc,
               float* __restrict__ pml)
{
    __shared__ __align__(16) __bf16 Kc3[3 * 32 * 64];   // 12KB
    __shared__ __align__(16) __bf16 Vc3[3 * 64 * 32];   // 12KB
    __shared__ __align__(16) float  ytl[3 * 32];        // 384B
    __shared__ __align__(16) __bf16 Pt[4][16 * 32];     // 4KB

    const int tid  = threadIdx.x;
    const int wave = tid >> 6;
    const int m16  = tid & 15;
    const int quad = (tid & 63) >> 4;
    const int qt = blockIdx.x, bh = blockIdx.y, split = blockIdx.z;
    const int b = bh / H_;
    const int qblk  = qt * 64;
    const int qbase = qblk + wave * 16;

    const float dist = (float)dist_p[0];
    const float md   = (float)min_dist_p[0];
    const float* yt = y_t + (size_t)b * TY_;
    const float* xt = x_t + (size_t)b * TX_;

    const float xtmin = xt[qblk] - md;
    const float xtmax = xt[qblk + 63] - md;
    int lo = 0, hi = TY_;
    while (lo < hi) { int mid = (lo + hi) >> 1; if (yt[mid] + dist < xtmin) lo = mid + 1; else hi = mid; }
    const int klo = lo;
    lo = 0; hi = TY_;
    while (lo < hi) { int mid = (lo + hi) >> 1; if (yt[mid] <= xtmax) lo = mid + 1; else hi = mid; }
    const int khi = lo - 1;
    const int len = khi - klo + 1;

    int k0 = klo, k1 = klo;
    if (len > 0) {
        const int cnt = (len + NSPLIT - 1) / NSPLIT;
        k0 = klo + split * cnt;
        k1 = min(k0 + cnt, klo + len);
    }
    const int nt = (k1 > k0) ? ((k1 - k0 + 31) >> 5) : 0;

    float xtq[4];
#pragma unroll
    for (int r = 0; r < 4; r++)
        xtq[r] = xt[qbase + quad * 4 + r] - md;

    const __bf16* qp = Qb + ((size_t)bh * TX_ + qbase + m16) * 64;
    const bf16x8 aq0 = *(const bf16x8*)(qp + quad * 8);
    const bf16x8 aq1 = *(const bf16x8*)(qp + 32 + quad * 8);

    float l[4];
    floatx4 o[4];
#pragma unroll
    for (int r = 0; r < 4; r++) l[r] = 0.f;
#pragma unroll
    for (int ot = 0; ot < 4; ot++) o[ot] = (floatx4){0.f, 0.f, 0.f, 0.f};

    // stage chunk c (kc = k0 + 32c) into buffer buf
    auto stageA = [&](int c, int buf) {
        const int kc = k0 + c * 32;
        const int krow = tid >> 3;
        const int kg = min(kc + krow, TY_ - 1);
        async_copy16(Kb + ((size_t)bh * TY_ + kg) * 64 + (tid & 7) * 8,
                     (char*)Kc3 + buf * 4096 + tid * 16);
        const int d = tid >> 2;
        const int kv = min(kc + (tid & 3) * 8, TY_ - 8);
        async_copy16(Vt + ((size_t)bh * 64 + d) * TY_ + kv,
                     (char*)Vc3 + buf * 4096 + tid * 16);
        if (tid < 32) {
            const int gk = min(kc + tid, TY_ - 1);
            async_copy4(yt + gk, (char*)ytl + buf * 128 + tid * 4);
        }
    };

    if (nt > 0) stageA(0, 0);
    if (nt > 1) stageA(1, 1);

    int cur = 0;
    for (int tc = 0; tc < nt; ++tc) {
        if (tc < nt - 1) {
            if (wave == 0) asm volatile("s_waitcnt vmcnt(3)" ::: "memory");
            else           asm volatile("s_waitcnt vmcnt(2)" ::: "memory");
        } else {
            asm volatile("s_waitcnt vmcnt(0)" ::: "memory");
        }
        __builtin_amdgcn_s_barrier();
        asm volatile("" ::: "memory");

        if (tc + 2 < nt) {
            int nb = cur + 2; if (nb >= 3) nb -= 3;
            stageA(tc + 2, nb);
        }

        const int kc = k0 + tc * 32;
        const __bf16* Kc = Kc3 + cur * 2048;
        const __bf16* Vc = Vc3 + cur * 2048;
        const float yt0 = ytl[cur * 32 + m16];
        const float yt1 = ytl[cur * 32 + 16 + m16];

        const bf16x8 bk0h0 = *(const bf16x8*)(Kc + m16 * 64 + quad * 8);
        const bf16x8 bk1h0 = *(const bf16x8*)(Kc + m16 * 64 + 32 + quad * 8);
        const bf16x8 bk0h1 = *(const bf16x8*)(Kc + (16 + m16) * 64 + quad * 8);
        const bf16x8 bk1h1 = *(const bf16x8*)(Kc + (16 + m16) * 64 + 32 + quad * 8);
        floatx4 s0 = (floatx4){0.f, 0.f, 0.f, 0.f};
        floatx4 s1 = (floatx4){0.f, 0.f, 0.f, 0.f};
        s0 = __builtin_amdgcn_mfma_f32_16x16x32_bf16(aq0, bk0h0, s0, 0, 0, 0);
        s0 = __builtin_amdgcn_mfma_f32_16x16x32_bf16(aq1, bk1h0, s0, 0, 0, 0);
        s1 = __builtin_amdgcn_mfma_f32_16x16x32_bf16(aq0, bk0h1, s1, 0, 0, 0);
        s1 = __builtin_amdgcn_mfma_f32_16x16x32_bf16(aq1, bk1h1, s1, 0, 0, 0);

        const int kg0 = kc + m16;
        const int kg1 = kc + 16 + m16;
        __bf16* pt = Pt[wave];
#pragma unroll
        for (int r = 0; r < 4; r++) {
            const bool v0 = (kg0 < k1) && (xtq[r] >= yt0) && (xtq[r] <= yt0 + dist);
            const bool v1 = (kg1 < k1) && (xtq[r] >= yt1) && (xtq[r] <= yt1 + dist);
            const float p0 = v0 ? (float)(__bf16)__expf(s0[r]) : 0.f;
            const float p1 = v1 ? (float)(__bf16)__expf(s1[r]) : 0.f;
            l[r] += p0 + p1;
            pt[(quad * 4 + r) * 32 + m16]      = (__bf16)p0;
            pt[(quad * 4 + r) * 32 + 16 + m16] = (__bf16)p1;
        }
        const bf16x8 ap = *(const bf16x8*)(pt + m16 * 32 + quad * 8);
#pragma unroll
        for (int ot = 0; ot < 4; ot++) {
            const bf16x8 bv = *(const bf16x8*)(Vc + (ot * 16 + m16) * 32 + quad * 8);
            o[ot] = __builtin_amdgcn_mfma_f32_16x16x32_bf16(ap, bv, o[ot], 0, 0, 0);
        }

        cur = (cur == 2) ? 0 : cur + 1;
    }

#pragma unroll
    for (int r = 0; r < 4; r++) {
#pragma unroll
        for (int w = 1; w < 16; w <<= 1)
            l[r] += __shfl_xor(l[r], w);
    }

#pragma unroll
    for (int ot = 0; ot < 4; ot++)
#pragma unroll
        for (int r = 0; r < 4; r++) {
            const size_t gr = (size_t)bh * TX_ + qbase + quad * 4 + r;
            pacc[((size_t)split * R_ + gr) * 64 + ot * 16 + m16] = o[ot][r];
        }
    if (m16 == 0) {
#pragma unroll
        for (int r = 0; r < 4; r++) {
            const size_t gr = (size_t)bh * TX_ + qbase + quad * 4 + r;
            pml[(size_t)split * R_ + gr] = l[r];
        }
    }
}

// ---------------------------------------------------------------------------
// Combine NSPLIT partials -> Ob bf16 (B,TX,C)
// ---------------------------------------------------------------------------
__global__ __launch_bounds__(256)
void combine_kernel(const float* __restrict__ pacc,
                    const float* __restrict__ pml,
                    __bf16* __restrict__ O)
{
    const int d   = threadIdx.x;
    const int sub = threadIdx.y;
    const size_t r = (size_t)blockIdx.x * 4 + sub;
    const int bh  = (int)(r / TX_);
    const int txg = (int)(r % TX_);
    const int b = bh / H_, h = bh % H_;

    float L = 0.f, val = 0.f;
#pragma unroll
    for (int s = 0; s < NSPLIT; s++) {
        L   += pml[(size_t)s * R_ + r];
        val += pacc[((size_t)s * R_ + r) * 64 + d];
    }
    const float o = (L > 0.f) ? val / L : 0.f;
    O[(size_t)(b * TX_ + txg) * C_ + h * D_ + d] = (__bf16)o;
}

// ---------------------------------------------------------------------------
// proj GEMM: out(M,768 f32) = A(M,768 bf16) @ Bt(768,768 bf16)^T
// NEW: 64x128 tile -> 192 blocks (2x CU coverage vs 96), depth-3 prefetch:
// 4 rotating 12KB buffers (48KB LDS), vmcnt(6/3/0) schedule, XCD swizzle
// (192 = 8*24). At <=1 block/CU the in-block pipeline is the only latency
// hiding -- so it is made deeper than qkv's.
// ---------------------------------------------------------------------------
__global__ __launch_bounds__(256)
void gemm_proj(const __bf16* __restrict__ A,
               const __bf16* __restrict__ Bt,
               float* __restrict__ out0)
{
    const int bid = (blockIdx.x & 7) * 24 + (blockIdx.x >> 3);
    const int row0 = (bid / 6) * 64;
    const int n0   = (bid % 6) * 128;

    __shared__ __align__(16) float smem_f[12288];   // 48KB = 4 x 12KB
    __bf16* smem_b = (__bf16*)smem_f;

    const int tid  = threadIdx.x;
    const int wave = tid >> 6;
    const int lane = tid & 63;
    const int m16  = lane & 15;
    const int quad = lane >> 4;
    const int wm   = wave >> 1;
    const int wn   = wave & 1;

    floatx4 acc[2][4];
#pragma unroll
    for (int i = 0; i < 2; i++)
#pragma unroll
        for (int j = 0; j < 4; j++) acc[i][j] = (floatx4){0.f, 0.f, 0.f, 0.f};

    const int eA = wave * 512 + lane * 8;
    const int srA = eA >> 5, scA = eA & 31;
    int srB[2], scB[2];
#pragma unroll
    for (int j = 0; j < 2; j++) {
        const int e = j * 2048 + wave * 512 + lane * 8;
        srB[j] = e >> 5; scB[j] = e & 31;
    }

    auto stage = [&](int chunk, int buf) {
        const int kk = chunk * 32;
        async_copy16(A + (size_t)(row0 + srA) * C_ + (kk + scA),
                     (char*)smem_f + buf * 12288 + wave * 1024);
#pragma unroll
        for (int j = 0; j < 2; j++)
            async_copy16(Bt + (size_t)(n0 + srB[j]) * C_ + (kk + scB[j]),
                         (char*)smem_f + buf * 12288 + 4096 + j * 4096 + wave * 1024);
    };

    stage(0, 0);
    stage(1, 1);
    stage(2, 2);

    for (int t = 0; t < 24; ++t) {
        if (t < 22)      asm volatile("s_waitcnt vmcnt(6)" ::: "memory");
        else if (t == 22) asm volatile("s_waitcnt vmcnt(3)" ::: "memory");
        else              asm volatile("s_waitcnt vmcnt(0)" ::: "memory");
        __builtin_amdgcn_s_barrier();
        asm volatile("" ::: "memory");

        if (t + 3 < 24) stage(t + 3, (t + 3) & 3);

        const __bf16* As = smem_b + (t & 3) * 6144;
        const __bf16* Bs = As + 2048;
        bf16x8 af[2], bfr[4];
#pragma unroll
        for (int i = 0; i < 2; i++)
            af[i] = *(const bf16x8*)(As + (size_t)(wm * 32 + i * 16 + m16) * 32 + quad * 8);
#pragma unroll
        for (int j = 0; j < 4; j++)
            bfr[j] = *(const bf16x8*)(Bs + (size_t)(wn * 64 + j * 16 + m16) * 32 + quad * 8);
#pragma unroll
        for (int i = 0; i < 2; i++)
#pragma unroll
            for (int j = 0; j < 4; j++)
                acc[i][j] = __builtin_amdgcn_mfma_f32_16x16x32_bf16(af[i], bfr[j], acc[i][j], 0, 0, 0);
    }

    const int STR = 132;
    float* fs = smem_f;
#pragma unroll
    for (int i = 0; i < 2; i++) {
        __syncthreads();
#pragma unroll
        for (int j = 0; j < 4; j++) {
            const int col_l = wn * 64 + j * 16 + m16;
#pragma unroll
            for (int r = 0; r < 4; r++)
                fs[(wm * 16 + quad * 4 + r) * STR + col_l] = acc[i][j][r];
        }
        __syncthreads();
        const int r32 = tid >> 3;
        const int lc  = (tid & 7) * 4;
        const int row = row0 + (r32 >> 4) * 32 + i * 16 + (r32 & 15);
        float* gp = out0 + (size_t)row * C_ + n0;
#pragma unroll
        for (int c2 = 0; c2 < 4; c2++) {
            float4 v4 = *(const float4*)&fs[r32 * STR + c2 * 32 + lc];
            *(float4*)(gp + c2 * 32 + lc) = v4;
        }
    }
}

// ---------------------------------------------------------------------------
extern "C" void kernel_launch(void* const* d_in, const int* in_sizes, int n_in,
                              void* d_out, int out_size, void* d_ws, size_t ws_size,
                              hipStream_t stream)
{
    const float* x        = (const float*)d_in[0];
    const float* x_t      = (const float*)d_in[1];
    const float* y        = (const float*)d_in[2];
    const float* y_t      = (const float*)d_in[3];
    const int*   dist     = (const int*)d_in[4];
    const int*   min_dist = (const int*)d_in[5];
    const float* Wq       = (const float*)d_in[6];
    const float* Wkv      = (const float*)d_in[7];
    const float* Wproj    = (const float*)d_in[8];
    const float* inv_freq = (const float*)d_in[9];
    float* out = (float*)d_out;

    const size_t QN = (size_t)B_ * TX_ * C_;
    const size_t KN = (size_t)B_ * TY_ * C_;

    float* ws = (float*)d_ws;
    float* pacc = ws; ws += (size_t)NSPLIT * R_ * 64;
    float* pml  = ws; ws += (size_t)NSPLIT * R_;
    __bf16* bws = (__bf16*)ws;
    __bf16* xb    = bws; bws += QN;
    __bf16* yb    = bws; bws += KN;
    __bf16* Wqt   = bws; bws += (size_t)C_ * C_;
    __bf16* Wkvt  = bws; bws += (size_t)C_ * 2 * C_;
    __bf16* Wprt  = bws; bws += (size_t)C_ * C_;
    __bf16* Ob    = bws; bws += QN;
    __bf16* Qbh   = bws; bws += QN;          // [bh][TX][64]
    __bf16* Kbh   = bws; bws += KN;          // [bh][TY][64]
    __bf16* Vtb   = bws; bws += KN + 128;    // [bh][64][TY]

    prep<<<dim3(2304 + 3840), dim3(256), 0, stream>>>(
        x, xb, y, yb, Wq, Wqt, Wkv, Wkvt, Wproj, Wprt);

    gemm_qkv<<<dim3(1728), dim3(256), 0, stream>>>(
        xb, Wqt, yb, Wkvt, Qbh, Kbh, Vtb, x_t, y_t, inv_freq);

    attn_mfma<<<dim3(TX_ / 64, B_ * H_, NSPLIT), dim3(256), 0, stream>>>(
        Qbh, Kbh, Vtb, x_t, y_t, dist, min_dist, pacc, pml);

    combine_kernel<<<dim3((unsigned)(R_ / 4)), dim3(64, 4), 0, stream>>>(
        pacc, pml, Ob);

    gemm_proj<<<dim3(192), dim3(256), 0, stream>>>(
        Ob, Wprt, out);
}

// Round 6
// 180.145 us; speedup vs baseline: 1.0875x; 1.0084x over previous
//
#include <hip/hip_runtime.h>
#include <hip/hip_bf16.h>
#include <math.h>

#define B_ 2
#define TX_ 1024
#define TY_ 4096
#define C_ 768
#define H_ 12
#define D_ 64
#define NSPLIT 2
#define R_ (B_ * H_ * TX_)

typedef __bf16 bf16x8 __attribute__((ext_vector_type(8)));
typedef float floatx4 __attribute__((ext_vector_type(4)));

__device__ __forceinline__ void async_copy16(const void* g, void* l) {
    __builtin_amdgcn_global_load_lds(
        (const __attribute__((address_space(1))) unsigned int*)g,
        (__attribute__((address_space(3))) unsigned int*)l,
        16, 0, 0);
}

__device__ __forceinline__ void async_copy4(const void* g, void* l) {
    __builtin_amdgcn_global_load_lds(
        (const __attribute__((address_space(1))) unsigned int*)g,
        (__attribute__((address_space(3))) unsigned int*)l,
        4, 0, 0);
}

__device__ __forceinline__ bf16x8 cvt8(const float* s) {
    bf16x8 r;
#pragma unroll
    for (int i = 0; i < 8; i++) r[i] = (__bf16)s[i];
    return r;
}

// ---------------------------------------------------------------------------
// prep (unchanged)
// ---------------------------------------------------------------------------
__global__ __launch_bounds__(256)
void prep(const float* __restrict__ x,  __bf16* __restrict__ xb,
          const float* __restrict__ y,  __bf16* __restrict__ yb,
          const float* __restrict__ Wq, __bf16* __restrict__ Wqt,
          const float* __restrict__ Wkv,__bf16* __restrict__ Wkvt,
          const float* __restrict__ Wpr,__bf16* __restrict__ Wprt)
{
    __shared__ float tile[32][33];
    const int bid = blockIdx.x;
    if (bid >= 2304) {
        const int cb = bid - 2304;
        const float* src; __bf16* dst; size_t base;
        if (cb < 768) { src = x; dst = xb; base = (size_t)cb * 2048; }
        else          { src = y; dst = yb; base = (size_t)(cb - 768) * 2048; }
        const size_t i = base + threadIdx.x * 8;
        float4 v0 = *(const float4*)(src + i);
        float4 v1 = *(const float4*)(src + i + 4);
        bf16x8 p;
        p[0] = (__bf16)v0.x; p[1] = (__bf16)v0.y; p[2] = (__bf16)v0.z; p[3] = (__bf16)v0.w;
        p[4] = (__bf16)v1.x; p[5] = (__bf16)v1.y; p[6] = (__bf16)v1.z; p[7] = (__bf16)v1.w;
        *(bf16x8*)(dst + i) = p;
        return;
    }
    const int bxr = bid % 96;
    const int byr = bid / 96;
    const float* W; __bf16* Wt; int N, nb; float scale = 1.0f;
    if (bxr < 24)      { W = Wq;  Wt = Wqt;  N = C_;     nb = bxr;      scale = 0.125f; }
    else if (bxr < 72) { W = Wkv; Wt = Wkvt; N = 2 * C_; nb = bxr - 24; }
    else               { W = Wpr; Wt = Wprt; N = C_;     nb = bxr - 72; }
    const int bx = nb * 32;
    const int by = byr * 32;
    const int tx = threadIdx.x & 31, ty = threadIdx.x >> 5;
#pragma unroll
    for (int i = 0; i < 4; i++)
        tile[ty + i * 8][tx] = W[(size_t)(by + ty + i * 8) * N + bx + tx];
    __syncthreads();
#pragma unroll
    for (int i = 0; i < 4; i++)
        Wt[(size_t)(bx + ty + i * 8) * C_ + by + tx] =
            (__bf16)(tile[tx][ty + i * 8] * scale);
}

// ---------------------------------------------------------------------------
// Fused Q + KV MFMA GEMM. r5 structure + T2 both-sides LDS swizzle:
// fragment rows stride 64B -> un-swizzled ds_read_b128 was 8-way bank
// conflicted. Fix: LDS stays linear (global_load_lds requirement), the
// GLOBAL source 16B-chunk index is XORed with (row>>1)&3 at staging, and
// the read applies the same XOR -> residual aliasing 2-way (free).
// Pure permutation: numerics identical.
// ---------------------------------------------------------------------------
__global__ __launch_bounds__(256)
void gemm_qkv(const __bf16* __restrict__ xb, const __bf16* __restrict__ Wqt,
              const __bf16* __restrict__ yb, const __bf16* __restrict__ Wkvt,
              __bf16* __restrict__ Qbh, __bf16* __restrict__ Kbh,
              __bf16* __restrict__ Vtb,
              const float* __restrict__ x_t, const float* __restrict__ y_t,
              const float* __restrict__ inv_freq)
{
    const int bid = (blockIdx.x & 7) * 216 + (blockIdx.x >> 3);
    const bool isQ = (bid < 192);
    const __bf16* A; const __bf16* Bt; const float* t_arr;
    int row0, n0, T, TSH;
    if (isQ) {
        A = xb; Bt = Wqt; t_arr = x_t;
        row0 = (bid / 6) * 64; n0 = (bid % 6) * 128; T = TX_; TSH = 10;
    } else {
        const int r = bid - 192;
        A = yb; Bt = Wkvt; t_arr = y_t;
        row0 = (r / 12) * 64; n0 = (r % 12) * 128; T = TY_; TSH = 12;
    }
    const bool isV = (!isQ) && (n0 >= C_);

    __shared__ __align__(16) float smem_f[9216];
    __bf16* smem_b = (__bf16*)smem_f;

    const int tid  = threadIdx.x;
    const int wave = tid >> 6;
    const int lane = tid & 63;
    const int m16  = lane & 15;
    const int quad = lane >> 4;
    const int wm   = wave >> 1;
    const int wn   = wave & 1;

    floatx4 acc[2][4];
#pragma unroll
    for (int i = 0; i < 2; i++)
#pragma unroll
        for (int j = 0; j < 4; j++) acc[i][j] = (floatx4){0.f, 0.f, 0.f, 0.f};

    // staging rows (unchanged) + swizzled source column offset:
    // lane's LDS slot = row (wave*16 + lane>>2), chunk (lane&3);
    // row's XOR key s = (row>>1)&3 = (lane>>3)&3  -> src col = (chunk^s)*8
    const int srA = wave * 16 + (lane >> 2);
    int srB[2];
#pragma unroll
    for (int j = 0; j < 2; j++) srB[j] = j * 64 + wave * 16 + (lane >> 2);
    const int scS = (((lane & 3) ^ ((lane >> 3) & 3))) * 8;

    auto stage = [&](int chunk, int buf) {
        const int kk = chunk * 32;
        async_copy16(A + (size_t)(row0 + srA) * C_ + (kk + scS),
                     (char*)smem_f + buf * 12288 + wave * 1024);
#pragma unroll
        for (int j = 0; j < 2; j++)
            async_copy16(Bt + (size_t)(n0 + srB[j]) * C_ + (kk + scS),
                         (char*)smem_f + buf * 12288 + 4096 + j * 4096 + wave * 1024);
    };

    stage(0, 0);
    stage(1, 1);

    const int sro = (m16 >> 1) & 3;   // read-side XOR key (rows base %16==0)

    int cur = 0;
    for (int t = 0; t < 24; ++t) {
        if (t < 23) asm volatile("s_waitcnt vmcnt(3)" ::: "memory");
        else        asm volatile("s_waitcnt vmcnt(0)" ::: "memory");
        __builtin_amdgcn_s_barrier();
        asm volatile("" ::: "memory");

        if (t + 2 < 24) {
            int nb = cur + 2; if (nb >= 3) nb -= 3;
            stage(t + 2, nb);
        }

        const __bf16* As = smem_b + cur * 6144;
        const __bf16* Bs = As + 2048;
        bf16x8 af[2], bfr[4];
#pragma unroll
        for (int i = 0; i < 2; i++)
            af[i] = *(const bf16x8*)(As + (size_t)(wm * 32 + i * 16 + m16) * 32 + ((quad ^ sro) * 8));
#pragma unroll
        for (int j = 0; j < 4; j++)
            bfr[j] = *(const bf16x8*)(Bs + (size_t)(wn * 64 + j * 16 + m16) * 32 + ((quad ^ sro) * 8));
#pragma unroll
        for (int i = 0; i < 2; i++)
#pragma unroll
            for (int j = 0; j < 4; j++)
                acc[i][j] = __builtin_amdgcn_mfma_f32_16x16x32_bf16(af[i], bfr[j], acc[i][j], 0, 0, 0);

        cur = (cur == 2) ? 0 : cur + 1;
    }

    const int STR = 132;
    float* fs = smem_f;

#pragma unroll
    for (int i = 0; i < 2; i++) {
        __syncthreads();
#pragma unroll
        for (int j = 0; j < 4; j++) {
            const int col_l = wn * 64 + j * 16 + m16;
#pragma unroll
            for (int r = 0; r < 4; r++) {
                const int row_l = quad * 4 + r;
                float v = acc[i][j][r];
                if (!isV) {
                    const float vp = __shfl_xor(v, 1);
                    const int row = row0 + wm * 32 + i * 16 + row_l;
                    const int cc = (n0 + col_l) & (D_ - 1);
                    const float fr = t_arr[row] * inv_freq[cc >> 1];
                    const float sn = __sinf(fr), cs = __cosf(fr);
                    v = (m16 & 1) ? (v * cs + vp * sn) : (v * cs - vp * sn);
                }
                fs[(wm * 16 + row_l) * STR + col_l] = v;
            }
        }
        __syncthreads();

        if (!isV) {
            __bf16* outb = isQ ? Qbh : Kbh;
            const int r32 = tid >> 3;
            const int lane8 = tid & 7;
            const int grow = row0 + (r32 >> 4) * 32 + i * 16 + (r32 & 15);
            const int bb = grow >> TSH;
            const int rk = grow & (T - 1);
            const int h  = (n0 >> 6) + (lane8 >> 2);
            const int d0 = (lane8 & 3) * 16;
            __bf16* gp = outb + ((size_t)(bb * H_ + h) * T + rk) * 64 + d0;
            const float* sp = &fs[r32 * STR + lane8 * 16];
            *(bf16x8*)gp       = cvt8(sp);
            *(bf16x8*)(gp + 8) = cvt8(sp + 8);
        } else {
            const int dcol = tid >> 1;
            const int g16  = tid & 1;
            const int h  = ((n0 - C_) >> 6) + (dcol >> 6);
            const int dd = dcol & 63;
            const int kbase = row0 + g16 * 32 + i * 16;
            const int bb  = kbase >> 12;
            const int kin = kbase & (TY_ - 1);
            float tmp[16];
#pragma unroll
            for (int jj = 0; jj < 16; jj++)
                tmp[jj] = fs[(g16 * 16 + jj) * STR + dcol];
            __bf16* gp = Vtb + ((size_t)(bb * H_ + h) * 64 + dd) * TY_ + kin;
            *(bf16x8*)gp       = cvt8(tmp);
            *(bf16x8*)(gp + 8) = cvt8(tmp + 8);
        }
    }
}

// ---------------------------------------------------------------------------
// MFMA flash attention. r5 pipeline + T2 swizzles:
//   K rows are 128B -> un-swizzled reads were 16-WAY bank conflicted
//     (bank = quad*4 for all m16). Fix: chunk ^= row&7 (8-way spread).
//   V and P rows are 64B -> 8-way. Fix: chunk ^= (row>>1)&3.
// All both-sides (swizzled global source / swizzled scalar write + swizzled
// read); pure permutations, numerics identical.
// ---------------------------------------------------------------------------
__global__ __launch_bounds__(256)
void attn_mfma(const __bf16* __restrict__ Qb,
               const __bf16* __restrict__ Kb,
               const __bf16* __restrict__ Vt,
               const float* __restrict__ x_t,
               const float* __restrict__ y_t,
               const int* __restrict__ dist_p,
               const int* __restrict__ min_dist_p,
               float* __restrict__ pacc,
               float* __restrict__ pml)
{
    __shared__ __align__(16) __bf16 Kc3[3 * 32 * 64];   // 12KB
    __shared__ __align__(16) __bf16 Vc3[3 * 64 * 32];   // 12KB
    __shared__ __align__(16) float  ytl[3 * 32];        // 384B
    __shared__ __align__(16) __bf16 Pt[4][16 * 32];     // 4KB

    const int tid  = threadIdx.x;
    const int wave = tid >> 6;
    const int m16  = tid & 15;
    const int quad = (tid & 63) >> 4;
    const int qt = blockIdx.x, bh = blockIdx.y, split = blockIdx.z;
    const int b = bh / H_;
    const int qblk  = qt * 64;
    const int qbase = qblk + wave * 16;

    const float dist = (float)dist_p[0];
    const float md   = (float)min_dist_p[0];
    const float* yt = y_t + (size_t)b * TY_;
    const float* xt = x_t + (size_t)b * TX_;

    const float xtmin = xt[qblk] - md;
    const float xtmax = xt[qblk + 63] - md;
    int lo = 0, hi = TY_;
    while (lo < hi) { int mid = (lo + hi) >> 1; if (yt[mid] + dist < xtmin) lo = mid + 1; else hi = mid; }
    const int klo = lo;
    lo = 0; hi = TY_;
    while (lo < hi) { int mid = (lo + hi) >> 1; if (yt[mid] <= xtmax) lo = mid + 1; else hi = mid; }
    const int khi = lo - 1;
    const int len = khi - klo + 1;

    int k0 = klo, k1 = klo;
    if (len > 0) {
        const int cnt = (len + NSPLIT - 1) / NSPLIT;
        k0 = klo + split * cnt;
        k1 = min(k0 + cnt, klo + len);
    }
    const int nt = (k1 > k0) ? ((k1 - k0 + 31) >> 5) : 0;

    float xtq[4];
#pragma unroll
    for (int r = 0; r < 4; r++)
        xtq[r] = xt[qbase + quad * 4 + r] - md;

    const __bf16* qp = Qb + ((size_t)bh * TX_ + qbase + m16) * 64;
    const bf16x8 aq0 = *(const bf16x8*)(qp + quad * 8);
    const bf16x8 aq1 = *(const bf16x8*)(qp + 32 + quad * 8);

    float l[4];
    floatx4 o[4];
#pragma unroll
    for (int r = 0; r < 4; r++) l[r] = 0.f;
#pragma unroll
    for (int ot = 0; ot < 4; ot++) o[ot] = (floatx4){0.f, 0.f, 0.f, 0.f};

    // staging swizzle keys (per-lane, row-derived)
    const int ksrc = (((tid & 7) ^ ((tid >> 3) & 7))) * 8;  // K: chunk^ (row&7)
    const int vchk = (tid & 3) ^ ((tid >> 3) & 3);          // V: chunk^((row>>1)&3)

    auto stageA = [&](int c, int buf) {
        const int kc = c * 32 + k0;
        const int krow = tid >> 3;
        const int kg = min(kc + krow, TY_ - 1);
        async_copy16(Kb + ((size_t)bh * TY_ + kg) * 64 + ksrc,
                     (char*)Kc3 + buf * 4096 + tid * 16);
        const int d = tid >> 2;
        const int kv = min(kc + vchk * 8, TY_ - 8);
        async_copy16(Vt + ((size_t)bh * 64 + d) * TY_ + kv,
                     (char*)Vc3 + buf * 4096 + tid * 16);
        if (tid < 32) {
            const int gk = min(kc + tid, TY_ - 1);
            async_copy4(yt + gk, (char*)ytl + buf * 128 + tid * 4);
        }
    };

    if (nt > 0) stageA(0, 0);
    if (nt > 1) stageA(1, 1);

    const int sk = m16 & 7;          // K read XOR key
    const int sv = (m16 >> 1) & 3;   // V / P read XOR key

    int cur = 0;
    for (int tc = 0; tc < nt; ++tc) {
        if (tc < nt - 1) {
            if (wave == 0) asm volatile("s_waitcnt vmcnt(3)" ::: "memory");
            else           asm volatile("s_waitcnt vmcnt(2)" ::: "memory");
        } else {
            asm volatile("s_waitcnt vmcnt(0)" ::: "memory");
        }
        __builtin_amdgcn_s_barrier();
        asm volatile("" ::: "memory");

        if (tc + 2 < nt) {
            int nb = cur + 2; if (nb >= 3) nb -= 3;
            stageA(tc + 2, nb);
        }

        const int kc = k0 + tc * 32;
        const __bf16* Kc = Kc3 + cur * 2048;
        const __bf16* Vc = Vc3 + cur * 2048;
        const float yt0 = ytl[cur * 32 + m16];
        const float yt1 = ytl[cur * 32 + 16 + m16];

        // K rows: 8 chunks of 16B; chunk q at logical (row, q^(row&7))
        const bf16x8 bk0h0 = *(const bf16x8*)(Kc + m16 * 64        + ((quad       ^ sk) * 8));
        const bf16x8 bk1h0 = *(const bf16x8*)(Kc + m16 * 64        + (((4 + quad) ^ sk) * 8));
        const bf16x8 bk0h1 = *(const bf16x8*)(Kc + (16 + m16) * 64 + ((quad       ^ sk) * 8));
        const bf16x8 bk1h1 = *(const bf16x8*)(Kc + (16 + m16) * 64 + (((4 + quad) ^ sk) * 8));
        floatx4 s0 = (floatx4){0.f, 0.f, 0.f, 0.f};
        floatx4 s1 = (floatx4){0.f, 0.f, 0.f, 0.f};
        s0 = __builtin_amdgcn_mfma_f32_16x16x32_bf16(aq0, bk0h0, s0, 0, 0, 0);
        s0 = __builtin_amdgcn_mfma_f32_16x16x32_bf16(aq1, bk1h0, s0, 0, 0, 0);
        s1 = __builtin_amdgcn_mfma_f32_16x16x32_bf16(aq0, bk0h1, s1, 0, 0, 0);
        s1 = __builtin_amdgcn_mfma_f32_16x16x32_bf16(aq1, bk1h1, s1, 0, 0, 0);

        const int kg0 = kc + m16;
        const int kg1 = kc + 16 + m16;
        __bf16* pt = Pt[wave];
#pragma unroll
        for (int r = 0; r < 4; r++) {
            const bool v0 = (kg0 < k1) && (xtq[r] >= yt0) && (xtq[r] <= yt0 + dist);
            const bool v1 = (kg1 < k1) && (xtq[r] >= yt1) && (xtq[r] <= yt1 + dist);
            const float p0 = v0 ? (float)(__bf16)__expf(s0[r]) : 0.f;
            const float p1 = v1 ? (float)(__bf16)__expf(s1[r]) : 0.f;
            l[r] += p0 + p1;
            const int prow = quad * 4 + r;
            const int sp = (prow >> 1) & 3;
            pt[prow * 32 + (((m16 >> 3) ^ sp) * 8)       + (m16 & 7)] = (__bf16)p0;
            pt[prow * 32 + ((((m16 >> 3) + 2) ^ sp) * 8) + (m16 & 7)] = (__bf16)p1;
        }
        const bf16x8 ap = *(const bf16x8*)(pt + m16 * 32 + ((quad ^ sv) * 8));
#pragma unroll
        for (int ot = 0; ot < 4; ot++) {
            const bf16x8 bv = *(const bf16x8*)(Vc + (ot * 16 + m16) * 32 + ((quad ^ sv) * 8));
            o[ot] = __builtin_amdgcn_mfma_f32_16x16x32_bf16(ap, bv, o[ot], 0, 0, 0);
        }

        cur = (cur == 2) ? 0 : cur + 1;
    }

#pragma unroll
    for (int r = 0; r < 4; r++) {
#pragma unroll
        for (int w = 1; w < 16; w <<= 1)
            l[r] += __shfl_xor(l[r], w);
    }

#pragma unroll
    for (int ot = 0; ot < 4; ot++)
#pragma unroll
        for (int r = 0; r < 4; r++) {
            const size_t gr = (size_t)bh * TX_ + qbase + quad * 4 + r;
            pacc[((size_t)split * R_ + gr) * 64 + ot * 16 + m16] = o[ot][r];
        }
    if (m16 == 0) {
#pragma unroll
        for (int r = 0; r < 4; r++) {
            const size_t gr = (size_t)bh * TX_ + qbase + quad * 4 + r;
            pml[(size_t)split * R_ + gr] = l[r];
        }
    }
}

// ---------------------------------------------------------------------------
// Combine NSPLIT partials -> Ob bf16 (B,TX,C)
// ---------------------------------------------------------------------------
__global__ __launch_bounds__(256)
void combine_kernel(const float* __restrict__ pacc,
                    const float* __restrict__ pml,
                    __bf16* __restrict__ O)
{
    const int d   = threadIdx.x;
    const int sub = threadIdx.y;
    const size_t r = (size_t)blockIdx.x * 4 + sub;
    const int bh  = (int)(r / TX_);
    const int txg = (int)(r % TX_);
    const int b = bh / H_, h = bh % H_;

    float L = 0.f, val = 0.f;
#pragma unroll
    for (int s = 0; s < NSPLIT; s++) {
        L   += pml[(size_t)s * R_ + r];
        val += pacc[((size_t)s * R_ + r) * 64 + d];
    }
    const float o = (L > 0.f) ? val / L : 0.f;
    O[(size_t)(b * TX_ + txg) * C_ + h * D_ + d] = (__bf16)o;
}

// ---------------------------------------------------------------------------
// proj GEMM (r5 structure: 64x128, 192 blocks, depth-3, XCD swizzle) + the
// same T2 LDS swizzle as gemm_qkv.
// ---------------------------------------------------------------------------
__global__ __launch_bounds__(256)
void gemm_proj(const __bf16* __restrict__ A,
               const __bf16* __restrict__ Bt,
               float* __restrict__ out0)
{
    const int bid = (blockIdx.x & 7) * 24 + (blockIdx.x >> 3);
    const int row0 = (bid / 6) * 64;
    const int n0   = (bid % 6) * 128;

    __shared__ __align__(16) float smem_f[12288];   // 48KB = 4 x 12KB
    __bf16* smem_b = (__bf16*)smem_f;

    const int tid  = threadIdx.x;
    const int wave = tid >> 6;
    const int lane = tid & 63;
    const int m16  = lane & 15;
    const int quad = lane >> 4;
    const int wm   = wave >> 1;
    const int wn   = wave & 1;

    floatx4 acc[2][4];
#pragma unroll
    for (int i = 0; i < 2; i++)
#pragma unroll
        for (int j = 0; j < 4; j++) acc[i][j] = (floatx4){0.f, 0.f, 0.f, 0.f};

    const int srA = wave * 16 + (lane >> 2);
    int srB[2];
#pragma unroll
    for (int j = 0; j < 2; j++) srB[j] = j * 64 + wave * 16 + (lane >> 2);
    const int scS = (((lane & 3) ^ ((lane >> 3) & 3))) * 8;

    auto stage = [&](int chunk, int buf) {
        const int kk = chunk * 32;
        async_copy16(A + (size_t)(row0 + srA) * C_ + (kk + scS),
                     (char*)smem_f + buf * 12288 + wave * 1024);
#pragma unroll
        for (int j = 0; j < 2; j++)
            async_copy16(Bt + (size_t)(n0 + srB[j]) * C_ + (kk + scS),
                         (char*)smem_f + buf * 12288 + 4096 + j * 4096 + wave * 1024);
    };

    stage(0, 0);
    stage(1, 1);
    stage(2, 2);

    const int sro = (m16 >> 1) & 3;

    for (int t = 0; t < 24; ++t) {
        if (t < 22)      asm volatile("s_waitcnt vmcnt(6)" ::: "memory");
        else if (t == 22) asm volatile("s_waitcnt vmcnt(3)" ::: "memory");
        else              asm volatile("s_waitcnt vmcnt(0)" ::: "memory");
        __builtin_amdgcn_s_barrier();
        asm volatile("" ::: "memory");

        if (t + 3 < 24) stage(t + 3, (t + 3) & 3);

        const __bf16* As = smem_b + (t & 3) * 6144;
        const __bf16* Bs = As + 2048;
        bf16x8 af[2], bfr[4];
#pragma unroll
        for (int i = 0; i < 2; i++)
            af[i] = *(const bf16x8*)(As + (size_t)(wm * 32 + i * 16 + m16) * 32 + ((quad ^ sro) * 8));
#pragma unroll
        for (int j = 0; j < 4; j++)
            bfr[j] = *(const bf16x8*)(Bs + (size_t)(wn * 64 + j * 16 + m16) * 32 + ((quad ^ sro) * 8));
#pragma unroll
        for (int i = 0; i < 2; i++)
#pragma unroll
            for (int j = 0; j < 4; j++)
                acc[i][j] = __builtin_amdgcn_mfma_f32_16x16x32_bf16(af[i], bfr[j], acc[i][j], 0, 0, 0);
    }

    const int STR = 132;
    float* fs = smem_f;
#pragma unroll
    for (int i = 0; i < 2; i++) {
        __syncthreads();
#pragma unroll
        for (int j = 0; j < 4; j++) {
            const int col_l = wn * 64 + j * 16 + m16;
#pragma unroll
            for (int r = 0; r < 4; r++)
                fs[(wm * 16 + quad * 4 + r) * STR + col_l] = acc[i][j][r];
        }
        __syncthreads();
        const int r32 = tid >> 3;
        const int lc  = (tid & 7) * 4;
        const int row = row0 + (r32 >> 4) * 32 + i * 16 + (r32 & 15);
        float* gp = out0 + (size_t)row * C_ + n0;
#pragma unroll
        for (int c2 = 0; c2 < 4; c2++) {
            float4 v4 = *(const float4*)&fs[r32 * STR + c2 * 32 + lc];
            *(float4*)(gp + c2 * 32 + lc) = v4;
        }
    }
}

// ---------------------------------------------------------------------------
extern "C" void kernel_launch(void* const* d_in, const int* in_sizes, int n_in,
                              void* d_out, int out_size, void* d_ws, size_t ws_size,
                              hipStream_t stream)
{
    const float* x        = (const float*)d_in[0];
    const float* x_t      = (const float*)d_in[1];
    const float* y        = (const float*)d_in[2];
    const float* y_t      = (const float*)d_in[3];
    const int*   dist     = (const int*)d_in[4];
    const int*   min_dist = (const int*)d_in[5];
    const float* Wq       = (const float*)d_in[6];
    const float* Wkv      = (const float*)d_in[7];
    const float* Wproj    = (const float*)d_in[8];
    const float* inv_freq = (const float*)d_in[9];
    float* out = (float*)d_out;

    const size_t QN = (size_t)B_ * TX_ * C_;
    const size_t KN = (size_t)B_ * TY_ * C_;

    float* ws = (float*)d_ws;
    float* pacc = ws; ws += (size_t)NSPLIT * R_ * 64;
    float* pml  = ws; ws += (size_t)NSPLIT * R_;
    __bf16* bws = (__bf16*)ws;
    __bf16* xb    = bws; bws += QN;
    __bf16* yb    = bws; bws += KN;
    __bf16* Wqt   = bws; bws += (size_t)C_ * C_;
    __bf16* Wkvt  = bws; bws += (size_t)C_ * 2 * C_;
    __bf16* Wprt  = bws; bws += (size_t)C_ * C_;
    __bf16* Ob    = bws; bws += QN;
    __bf16* Qbh   = bws; bws += QN;          // [bh][TX][64]
    __bf16* Kbh   = bws; bws += KN;          // [bh][TY][64]
    __bf16* Vtb   = bws; bws += KN + 128;    // [bh][64][TY]

    prep<<<dim3(2304 + 3840), dim3(256), 0, stream>>>(
        x, xb, y, yb, Wq, Wqt, Wkv, Wkvt, Wproj, Wprt);

    gemm_qkv<<<dim3(1728), dim3(256), 0, stream>>>(
        xb, Wqt, yb, Wkvt, Qbh, Kbh, Vtb, x_t, y_t, inv_freq);

    attn_mfma<<<dim3(TX_ / 64, B_ * H_, NSPLIT), dim3(256), 0, stream>>>(
        Qbh, Kbh, Vtb, x_t, y_t, dist, min_dist, pacc, pml);

    combine_kernel<<<dim3((unsigned)(R_ / 4)), dim3(64, 4), 0, stream>>>(
        pacc, pml, Ob);

    gemm_proj<<<dim3(192), dim3(256), 0, stream>>>(
        Ob, Wprt, out);
}

// Round 7
// 176.031 us; speedup vs baseline: 1.1130x; 1.0234x over previous
//
#include <hip/hip_runtime.h>
#include <hip/hip_bf16.h>
#include <math.h>

#define B_ 2
#define TX_ 1024
#define TY_ 4096
#define C_ 768
#define H_ 12
#define D_ 64
#define R_ (B_ * H_ * TX_)

typedef __bf16 bf16x8 __attribute__((ext_vector_type(8)));
typedef float floatx4 __attribute__((ext_vector_type(4)));

__device__ __forceinline__ void async_copy16(const void* g, void* l) {
    __builtin_amdgcn_global_load_lds(
        (const __attribute__((address_space(1))) unsigned int*)g,
        (__attribute__((address_space(3))) unsigned int*)l,
        16, 0, 0);
}

__device__ __forceinline__ void async_copy4(const void* g, void* l) {
    __builtin_amdgcn_global_load_lds(
        (const __attribute__((address_space(1))) unsigned int*)g,
        (__attribute__((address_space(3))) unsigned int*)l,
        4, 0, 0);
}

__device__ __forceinline__ bf16x8 cvt8(const float* s) {
    bf16x8 r;
#pragma unroll
    for (int i = 0; i < 8; i++) r[i] = (__bf16)s[i];
    return r;
}

// ---------------------------------------------------------------------------
// prep (unchanged)
// ---------------------------------------------------------------------------
__global__ __launch_bounds__(256)
void prep(const float* __restrict__ x,  __bf16* __restrict__ xb,
          const float* __restrict__ y,  __bf16* __restrict__ yb,
          const float* __restrict__ Wq, __bf16* __restrict__ Wqt,
          const float* __restrict__ Wkv,__bf16* __restrict__ Wkvt,
          const float* __restrict__ Wpr,__bf16* __restrict__ Wprt)
{
    __shared__ float tile[32][33];
    const int bid = blockIdx.x;
    if (bid >= 2304) {
        const int cb = bid - 2304;
        const float* src; __bf16* dst; size_t base;
        if (cb < 768) { src = x; dst = xb; base = (size_t)cb * 2048; }
        else          { src = y; dst = yb; base = (size_t)(cb - 768) * 2048; }
        const size_t i = base + threadIdx.x * 8;
        float4 v0 = *(const float4*)(src + i);
        float4 v1 = *(const float4*)(src + i + 4);
        bf16x8 p;
        p[0] = (__bf16)v0.x; p[1] = (__bf16)v0.y; p[2] = (__bf16)v0.z; p[3] = (__bf16)v0.w;
        p[4] = (__bf16)v1.x; p[5] = (__bf16)v1.y; p[6] = (__bf16)v1.z; p[7] = (__bf16)v1.w;
        *(bf16x8*)(dst + i) = p;
        return;
    }
    const int bxr = bid % 96;
    const int byr = bid / 96;
    const float* W; __bf16* Wt; int N, nb; float scale = 1.0f;
    if (bxr < 24)      { W = Wq;  Wt = Wqt;  N = C_;     nb = bxr;      scale = 0.125f; }
    else if (bxr < 72) { W = Wkv; Wt = Wkvt; N = 2 * C_; nb = bxr - 24; }
    else               { W = Wpr; Wt = Wprt; N = C_;     nb = bxr - 72; }
    const int bx = nb * 32;
    const int by = byr * 32;
    const int tx = threadIdx.x & 31, ty = threadIdx.x >> 5;
#pragma unroll
    for (int i = 0; i < 4; i++)
        tile[ty + i * 8][tx] = W[(size_t)(by + ty + i * 8) * N + bx + tx];
    __syncthreads();
#pragma unroll
    for (int i = 0; i < 4; i++)
        Wt[(size_t)(bx + ty + i * 8) * C_ + by + tx] =
            (__bf16)(tile[tx][ty + i * 8] * scale);
}

// ---------------------------------------------------------------------------
// Fused Q + KV MFMA GEMM -- ROUND-4 BANKED VERSION (50.7us): 64x128 tile,
// 24 chunks of 32-k, 3 rotating 12KB buffers (36KB), one barrier/chunk,
// counted vmcnt(3), XCD-bijective swizzle, LINEAR LDS (r6 proved the read
// swizzle costs +3.5us here: bank conflicts are off the critical path).
// ---------------------------------------------------------------------------
__global__ __launch_bounds__(256)
void gemm_qkv(const __bf16* __restrict__ xb, const __bf16* __restrict__ Wqt,
              const __bf16* __restrict__ yb, const __bf16* __restrict__ Wkvt,
              __bf16* __restrict__ Qbh, __bf16* __restrict__ Kbh,
              __bf16* __restrict__ Vtb,
              const float* __restrict__ x_t, const float* __restrict__ y_t,
              const float* __restrict__ inv_freq)
{
    const int bid = (blockIdx.x & 7) * 216 + (blockIdx.x >> 3);
    const bool isQ = (bid < 192);
    const __bf16* A; const __bf16* Bt; const float* t_arr;
    int row0, n0, T, TSH;
    if (isQ) {
        A = xb; Bt = Wqt; t_arr = x_t;
        row0 = (bid / 6) * 64; n0 = (bid % 6) * 128; T = TX_; TSH = 10;
    } else {
        const int r = bid - 192;
        A = yb; Bt = Wkvt; t_arr = y_t;
        row0 = (r / 12) * 64; n0 = (r % 12) * 128; T = TY_; TSH = 12;
    }
    const bool isV = (!isQ) && (n0 >= C_);

    __shared__ __align__(16) float smem_f[9216];
    __bf16* smem_b = (__bf16*)smem_f;

    const int tid  = threadIdx.x;
    const int wave = tid >> 6;
    const int lane = tid & 63;
    const int m16  = lane & 15;
    const int quad = lane >> 4;
    const int wm   = wave >> 1;
    const int wn   = wave & 1;

    floatx4 acc[2][4];
#pragma unroll
    for (int i = 0; i < 2; i++)
#pragma unroll
        for (int j = 0; j < 4; j++) acc[i][j] = (floatx4){0.f, 0.f, 0.f, 0.f};

    const int eA = wave * 512 + lane * 8;
    const int srA = eA >> 5, scA = eA & 31;
    int srB[2], scB[2];
#pragma unroll
    for (int j = 0; j < 2; j++) {
        const int e = j * 2048 + wave * 512 + lane * 8;
        srB[j] = e >> 5; scB[j] = e & 31;
    }

    auto stage = [&](int chunk, int buf) {
        const int kk = chunk * 32;
        async_copy16(A + (size_t)(row0 + srA) * C_ + (kk + scA),
                     (char*)smem_f + buf * 12288 + wave * 1024);
#pragma unroll
        for (int j = 0; j < 2; j++)
            async_copy16(Bt + (size_t)(n0 + srB[j]) * C_ + (kk + scB[j]),
                         (char*)smem_f + buf * 12288 + 4096 + j * 4096 + wave * 1024);
    };

    stage(0, 0);
    stage(1, 1);

    int cur = 0;
    for (int t = 0; t < 24; ++t) {
        if (t < 23) asm volatile("s_waitcnt vmcnt(3)" ::: "memory");
        else        asm volatile("s_waitcnt vmcnt(0)" ::: "memory");
        __builtin_amdgcn_s_barrier();
        asm volatile("" ::: "memory");

        if (t + 2 < 24) {
            int nb = cur + 2; if (nb >= 3) nb -= 3;
            stage(t + 2, nb);
        }

        const __bf16* As = smem_b + cur * 6144;
        const __bf16* Bs = As + 2048;
        bf16x8 af[2], bfr[4];
#pragma unroll
        for (int i = 0; i < 2; i++)
            af[i] = *(const bf16x8*)(As + (size_t)(wm * 32 + i * 16 + m16) * 32 + quad * 8);
#pragma unroll
        for (int j = 0; j < 4; j++)
            bfr[j] = *(const bf16x8*)(Bs + (size_t)(wn * 64 + j * 16 + m16) * 32 + quad * 8);
#pragma unroll
        for (int i = 0; i < 2; i++)
#pragma unroll
            for (int j = 0; j < 4; j++)
                acc[i][j] = __builtin_amdgcn_mfma_f32_16x16x32_bf16(af[i], bfr[j], acc[i][j], 0, 0, 0);

        cur = (cur == 2) ? 0 : cur + 1;
    }

    const int STR = 132;
    float* fs = smem_f;

#pragma unroll
    for (int i = 0; i < 2; i++) {
        __syncthreads();
#pragma unroll
        for (int j = 0; j < 4; j++) {
            const int col_l = wn * 64 + j * 16 + m16;
#pragma unroll
            for (int r = 0; r < 4; r++) {
                const int row_l = quad * 4 + r;
                float v = acc[i][j][r];
                if (!isV) {
                    const float vp = __shfl_xor(v, 1);
                    const int row = row0 + wm * 32 + i * 16 + row_l;
                    const int cc = (n0 + col_l) & (D_ - 1);
                    const float fr = t_arr[row] * inv_freq[cc >> 1];
                    const float sn = __sinf(fr), cs = __cosf(fr);
                    v = (m16 & 1) ? (v * cs + vp * sn) : (v * cs - vp * sn);
                }
                fs[(wm * 16 + row_l) * STR + col_l] = v;
            }
        }
        __syncthreads();

        if (!isV) {
            __bf16* outb = isQ ? Qbh : Kbh;
            const int r32 = tid >> 3;
            const int lane8 = tid & 7;
            const int grow = row0 + (r32 >> 4) * 32 + i * 16 + (r32 & 15);
            const int bb = grow >> TSH;
            const int rk = grow & (T - 1);
            const int h  = (n0 >> 6) + (lane8 >> 2);
            const int d0 = (lane8 & 3) * 16;
            __bf16* gp = outb + ((size_t)(bb * H_ + h) * T + rk) * 64 + d0;
            const float* sp = &fs[r32 * STR + lane8 * 16];
            *(bf16x8*)gp       = cvt8(sp);
            *(bf16x8*)(gp + 8) = cvt8(sp + 8);
        } else {
            const int dcol = tid >> 1;
            const int g16  = tid & 1;
            const int h  = ((n0 - C_) >> 6) + (dcol >> 6);
            const int dd = dcol & 63;
            const int kbase = row0 + g16 * 32 + i * 16;
            const int bb  = kbase >> 12;
            const int kin = kbase & (TY_ - 1);
            float tmp[16];
#pragma unroll
            for (int jj = 0; jj < 16; jj++)
                tmp[jj] = fs[(g16 * 16 + jj) * STR + dcol];
            __bf16* gp = Vtb + ((size_t)(bb * H_ + h) * 64 + dd) * TY_ + kin;
            *(bf16x8*)gp       = cvt8(tmp);
            *(bf16x8*)(gp + 8) = cvt8(tmp + 8);
        }
    }
}

// ---------------------------------------------------------------------------
// MFMA flash attention with IN-BLOCK SPLIT-COMBINE: 512 threads = two 4-wave
// groups; group g runs split g of the k-window with the r6-proven pipeline
// (3 rotating buffers, 1 barrier/chunk, counted vmcnt, K/V/P LDS swizzles).
// Both groups iterate ntmax chunks (block barriers stay convergent; the
// kg<k1 masks zero out the overrun, so stale-LDS iterations are no-ops).
// Ends with an LDS o/l merge and a direct coalesced bf16 Ob write --
// combine_kernel and the pacc/pml roundtrip are gone.
// ---------------------------------------------------------------------------
__global__ __launch_bounds__(512)
void attn_mfma(const __bf16* __restrict__ Qb,
               const __bf16* __restrict__ Kb,
               const __bf16* __restrict__ Vt,
               const float* __restrict__ x_t,
               const float* __restrict__ y_t,
               const int* __restrict__ dist_p,
               const int* __restrict__ min_dist_p,
               __bf16* __restrict__ Ob)
{
    __shared__ __align__(16) __bf16 Kc3[2][3 * 32 * 64];   // 24KB
    __shared__ __align__(16) __bf16 Vc3[2][3 * 64 * 32];   // 24KB
    __shared__ __align__(16) float  ytl[2][3 * 32];        // 768B
    __shared__ __align__(16) __bf16 Pt[8][16 * 32];        // 8KB
    __shared__ __align__(16) float  ex_o[64][66];          // ~16.5KB (padded)
    __shared__ float ex_l[64];

    const int tid  = threadIdx.x;          // 0..511
    const int wave = tid >> 6;             // 0..7
    const int g    = wave >> 2;            // split group
    const int w4   = wave & 3;
    const int t256 = tid & 255;            // index within group
    const int lane = tid & 63;
    const int m16  = lane & 15;
    const int quad = lane >> 4;
    const int qt = blockIdx.x, bh = blockIdx.y;
    const int b = bh / H_;
    const int h = bh % H_;
    const int qblk  = qt * 64;
    const int qbase = qblk + w4 * 16;

    const float dist = (float)dist_p[0];
    const float md   = (float)min_dist_p[0];
    const float* yt = y_t + (size_t)b * TY_;
    const float* xt = x_t + (size_t)b * TX_;

    const float xtmin = xt[qblk] - md;
    const float xtmax = xt[qblk + 63] - md;
    int lo = 0, hi = TY_;
    while (lo < hi) { int mid = (lo + hi) >> 1; if (yt[mid] + dist < xtmin) lo = mid + 1; else hi = mid; }
    const int klo = lo;
    lo = 0; hi = TY_;
    while (lo < hi) { int mid = (lo + hi) >> 1; if (yt[mid] <= xtmax) lo = mid + 1; else hi = mid; }
    const int khi = lo - 1;
    const int len = khi - klo + 1;

    // both split ranges computed by every thread (uniform ntmax)
    int k0g = klo, k1g = klo, nt0 = 0, nt1 = 0;
    if (len > 0) {
        const int cnt = (len + 1) >> 1;
        nt0 = (cnt + 31) >> 5;
        nt1 = (len - cnt + 31) >> 5;
        if (g == 0) { k0g = klo;       k1g = klo + cnt; }
        else        { k0g = klo + cnt; k1g = klo + len; }
    }
    const int ntg   = (g == 0) ? nt0 : nt1;
    const int ntmax = (nt0 > nt1) ? nt0 : nt1;

    float xtq[4];
#pragma unroll
    for (int r = 0; r < 4; r++)
        xtq[r] = xt[qbase + quad * 4 + r] - md;

    const __bf16* qp = Qb + ((size_t)bh * TX_ + qbase + m16) * 64;
    const bf16x8 aq0 = *(const bf16x8*)(qp + quad * 8);
    const bf16x8 aq1 = *(const bf16x8*)(qp + 32 + quad * 8);

    float l[4];
    floatx4 o[4];
#pragma unroll
    for (int r = 0; r < 4; r++) l[r] = 0.f;
#pragma unroll
    for (int ot = 0; ot < 4; ot++) o[ot] = (floatx4){0.f, 0.f, 0.f, 0.f};

    // staging swizzle keys (per-lane, row-derived, within group)
    const int ksrc = (((t256 & 7) ^ ((t256 >> 3) & 7))) * 8;  // K: chunk^(row&7)
    const int vchk = (t256 & 3) ^ ((t256 >> 3) & 3);          // V: chunk^((row>>1)&3)

    auto stageA = [&](int c, int buf) {
        const int kc = k0g + c * 32;
        const int krow = t256 >> 3;
        const int kg = min(kc + krow, TY_ - 1);
        async_copy16(Kb + ((size_t)bh * TY_ + kg) * 64 + ksrc,
                     (char*)Kc3[g] + buf * 4096 + t256 * 16);
        const int d = t256 >> 2;
        const int kv = min(kc + vchk * 8, TY_ - 8);
        async_copy16(Vt + ((size_t)bh * 64 + d) * TY_ + kv,
                     (char*)Vc3[g] + buf * 4096 + t256 * 16);
        if (t256 < 32) {
            const int gk = min(kc + t256, TY_ - 1);
            async_copy4(yt + gk, (char*)ytl[g] + buf * 128 + t256 * 4);
        }
    };

    if (ntg > 0) stageA(0, 0);
    if (ntg > 1) stageA(1, 1);

    const int sk = m16 & 7;          // K read XOR key
    const int sv = (m16 >> 1) & 3;   // V / P read XOR key

    int cur = 0;
    for (int tc = 0; tc < ntmax; ++tc) {
        if (tc < ntmax - 1) {
            if (w4 == 0) asm volatile("s_waitcnt vmcnt(3)" ::: "memory");
            else         asm volatile("s_waitcnt vmcnt(2)" ::: "memory");
        } else {
            asm volatile("s_waitcnt vmcnt(0)" ::: "memory");
        }
        __builtin_amdgcn_s_barrier();
        asm volatile("" ::: "memory");

        if (tc + 2 < ntg) {
            int nb = cur + 2; if (nb >= 3) nb -= 3;
            stageA(tc + 2, nb);
        }

        const int kc = k0g + tc * 32;
        const __bf16* Kc = Kc3[g] + cur * 2048;
        const __bf16* Vc = Vc3[g] + cur * 2048;
        const float yt0 = ytl[g][cur * 32 + m16];
        const float yt1 = ytl[g][cur * 32 + 16 + m16];

        const bf16x8 bk0h0 = *(const bf16x8*)(Kc + m16 * 64        + ((quad       ^ sk) * 8));
        const bf16x8 bk1h0 = *(const bf16x8*)(Kc + m16 * 64        + (((4 + quad) ^ sk) * 8));
        const bf16x8 bk0h1 = *(const bf16x8*)(Kc + (16 + m16) * 64 + ((quad       ^ sk) * 8));
        const bf16x8 bk1h1 = *(const bf16x8*)(Kc + (16 + m16) * 64 + (((4 + quad) ^ sk) * 8));
        floatx4 s0 = (floatx4){0.f, 0.f, 0.f, 0.f};
        floatx4 s1 = (floatx4){0.f, 0.f, 0.f, 0.f};
        s0 = __builtin_amdgcn_mfma_f32_16x16x32_bf16(aq0, bk0h0, s0, 0, 0, 0);
        s0 = __builtin_amdgcn_mfma_f32_16x16x32_bf16(aq1, bk1h0, s0, 0, 0, 0);
        s1 = __builtin_amdgcn_mfma_f32_16x16x32_bf16(aq0, bk0h1, s1, 0, 0, 0);
        s1 = __builtin_amdgcn_mfma_f32_16x16x32_bf16(aq1, bk1h1, s1, 0, 0, 0);

        const int kg0 = kc + m16;
        const int kg1 = kc + 16 + m16;
        __bf16* pt = Pt[wave];
#pragma unroll
        for (int r = 0; r < 4; r++) {
            const bool v0 = (kg0 < k1g) && (xtq[r] >= yt0) && (xtq[r] <= yt0 + dist);
            const bool v1 = (kg1 < k1g) && (xtq[r] >= yt1) && (xtq[r] <= yt1 + dist);
            const float p0 = v0 ? (float)(__bf16)__expf(s0[r]) : 0.f;
            const float p1 = v1 ? (float)(__bf16)__expf(s1[r]) : 0.f;
            l[r] += p0 + p1;
            const int prow = quad * 4 + r;
            const int sp = (prow >> 1) & 3;
            pt[prow * 32 + (((m16 >> 3) ^ sp) * 8)       + (m16 & 7)] = (__bf16)p0;
            pt[prow * 32 + ((((m16 >> 3) + 2) ^ sp) * 8) + (m16 & 7)] = (__bf16)p1;
        }
        const bf16x8 ap = *(const bf16x8*)(pt + m16 * 32 + ((quad ^ sv) * 8));
#pragma unroll
        for (int ot = 0; ot < 4; ot++) {
            const bf16x8 bv = *(const bf16x8*)(Vc + (ot * 16 + m16) * 32 + ((quad ^ sv) * 8));
            o[ot] = __builtin_amdgcn_mfma_f32_16x16x32_bf16(ap, bv, o[ot], 0, 0, 0);
        }

        cur = (cur == 2) ? 0 : cur + 1;
    }

    // per-wave row-sum reduce of l (over the 16-lane m16 dimension)
#pragma unroll
    for (int r = 0; r < 4; r++) {
#pragma unroll
        for (int w = 1; w < 16; w <<= 1)
            l[r] += __shfl_xor(l[r], w);
    }

    // ---- in-block split merge: group 1 publishes, group 0 accumulates
    if (g == 1) {
#pragma unroll
        for (int ot = 0; ot < 4; ot++)
#pragma unroll
            for (int r = 0; r < 4; r++)
                ex_o[w4 * 16 + quad * 4 + r][ot * 16 + m16] = o[ot][r];
        if (m16 == 0) {
#pragma unroll
            for (int r = 0; r < 4; r++)
                ex_l[w4 * 16 + quad * 4 + r] = l[r];
        }
    }
    __syncthreads();
    if (g == 0) {
#pragma unroll
        for (int ot = 0; ot < 4; ot++)
#pragma unroll
            for (int r = 0; r < 4; r++)
                ex_o[w4 * 16 + quad * 4 + r][ot * 16 + m16] += o[ot][r];
        if (m16 == 0) {
#pragma unroll
            for (int r = 0; r < 4; r++)
                ex_l[w4 * 16 + quad * 4 + r] += l[r];
        }
    }
    __syncthreads();

    // cooperative coalesced store: 512 lanes x 8 d-values
    {
        const int q  = tid >> 3;            // 0..63
        const int d0 = (tid & 7) * 8;
        const float L = ex_l[q];
        const float inv = (L > 0.f) ? 1.f / L : 0.f;
        float tmp[8];
#pragma unroll
        for (int j = 0; j < 8; j++) tmp[j] = ex_o[q][d0 + j] * inv;
        __bf16* gp = Ob + ((size_t)(b * TX_ + qblk + q)) * C_ + h * 64 + d0;
        *(bf16x8*)gp = cvt8(tmp);
    }
}

// ---------------------------------------------------------------------------
// proj GEMM (round-5 version: 64x128, 192 blocks, depth-3 prefetch, XCD
// swizzle, LINEAR LDS -- read swizzle reverted per the qkv r6 verdict).
// ---------------------------------------------------------------------------
__global__ __launch_bounds__(256)
void gemm_proj(const __bf16* __restrict__ A,
               const __bf16* __restrict__ Bt,
               float* __restrict__ out0)
{
    const int bid = (blockIdx.x & 7) * 24 + (blockIdx.x >> 3);
    const int row0 = (bid / 6) * 64;
    const int n0   = (bid % 6) * 128;

    __shared__ __align__(16) float smem_f[12288];   // 48KB = 4 x 12KB
    __bf16* smem_b = (__bf16*)smem_f;

    const int tid  = threadIdx.x;
    const int wave = tid >> 6;
    const int lane = tid & 63;
    const int m16  = lane & 15;
    const int quad = lane >> 4;
    const int wm   = wave >> 1;
    const int wn   = wave & 1;

    floatx4 acc[2][4];
#pragma unroll
    for (int i = 0; i < 2; i++)
#pragma unroll
        for (int j = 0; j < 4; j++) acc[i][j] = (floatx4){0.f, 0.f, 0.f, 0.f};

    const int eA = wave * 512 + lane * 8;
    const int srA = eA >> 5, scA = eA & 31;
    int srB[2], scB[2];
#pragma unroll
    for (int j = 0; j < 2; j++) {
        const int e = j * 2048 + wave * 512 + lane * 8;
        srB[j] = e >> 5; scB[j] = e & 31;
    }

    auto stage = [&](int chunk, int buf) {
        const int kk = chunk * 32;
        async_copy16(A + (size_t)(row0 + srA) * C_ + (kk + scA),
                     (char*)smem_f + buf * 12288 + wave * 1024);
#pragma unroll
        for (int j = 0; j < 2; j++)
            async_copy16(Bt + (size_t)(n0 + srB[j]) * C_ + (kk + scB[j]),
                         (char*)smem_f + buf * 12288 + 4096 + j * 4096 + wave * 1024);
    };

    stage(0, 0);
    stage(1, 1);
    stage(2, 2);

    for (int t = 0; t < 24; ++t) {
        if (t < 22)       asm volatile("s_waitcnt vmcnt(6)" ::: "memory");
        else if (t == 22) asm volatile("s_waitcnt vmcnt(3)" ::: "memory");
        else              asm volatile("s_waitcnt vmcnt(0)" ::: "memory");
        __builtin_amdgcn_s_barrier();
        asm volatile("" ::: "memory");

        if (t + 3 < 24) stage(t + 3, (t + 3) & 3);

        const __bf16* As = smem_b + (t & 3) * 6144;
        const __bf16* Bs = As + 2048;
        bf16x8 af[2], bfr[4];
#pragma unroll
        for (int i = 0; i < 2; i++)
            af[i] = *(const bf16x8*)(As + (size_t)(wm * 32 + i * 16 + m16) * 32 + quad * 8);
#pragma unroll
        for (int j = 0; j < 4; j++)
            bfr[j] = *(const bf16x8*)(Bs + (size_t)(wn * 64 + j * 16 + m16) * 32 + quad * 8);
#pragma unroll
        for (int i = 0; i < 2; i++)
#pragma unroll
            for (int j = 0; j < 4; j++)
                acc[i][j] = __builtin_amdgcn_mfma_f32_16x16x32_bf16(af[i], bfr[j], acc[i][j], 0, 0, 0);
    }

    const int STR = 132;
    float* fs = smem_f;
#pragma unroll
    for (int i = 0; i < 2; i++) {
        __syncthreads();
#pragma unroll
        for (int j = 0; j < 4; j++) {
            const int col_l = wn * 64 + j * 16 + m16;
#pragma unroll
            for (int r = 0; r < 4; r++)
                fs[(wm * 16 + quad * 4 + r) * STR + col_l] = acc[i][j][r];
        }
        __syncthreads();
        const int r32 = tid >> 3;
        const int lc  = (tid & 7) * 4;
        const int row = row0 + (r32 >> 4) * 32 + i * 16 + (r32 & 15);
        float* gp = out0 + (size_t)row * C_ + n0;
#pragma unroll
        for (int c2 = 0; c2 < 4; c2++) {
            float4 v4 = *(const float4*)&fs[r32 * STR + c2 * 32 + lc];
            *(float4*)(gp + c2 * 32 + lc) = v4;
        }
    }
}

// ---------------------------------------------------------------------------
extern "C" void kernel_launch(void* const* d_in, const int* in_sizes, int n_in,
                              void* d_out, int out_size, void* d_ws, size_t ws_size,
                              hipStream_t stream)
{
    const float* x        = (const float*)d_in[0];
    const float* x_t      = (const float*)d_in[1];
    const float* y        = (const float*)d_in[2];
    const float* y_t      = (const float*)d_in[3];
    const int*   dist     = (const int*)d_in[4];
    const int*   min_dist = (const int*)d_in[5];
    const float* Wq       = (const float*)d_in[6];
    const float* Wkv      = (const float*)d_in[7];
    const float* Wproj    = (const float*)d_in[8];
    const float* inv_freq = (const float*)d_in[9];
    float* out = (float*)d_out;

    const size_t QN = (size_t)B_ * TX_ * C_;
    const size_t KN = (size_t)B_ * TY_ * C_;

    __bf16* bws = (__bf16*)d_ws;
    __bf16* xb    = bws; bws += QN;
    __bf16* yb    = bws; bws += KN;
    __bf16* Wqt   = bws; bws += (size_t)C_ * C_;
    __bf16* Wkvt  = bws; bws += (size_t)C_ * 2 * C_;
    __bf16* Wprt  = bws; bws += (size_t)C_ * C_;
    __bf16* Ob    = bws; bws += QN;
    __bf16* Qbh   = bws; bws += QN;          // [bh][TX][64]
    __bf16* Kbh   = bws; bws += KN;          // [bh][TY][64]
    __bf16* Vtb   = bws; bws += KN + 128;    // [bh][64][TY]

    prep<<<dim3(2304 + 3840), dim3(256), 0, stream>>>(
        x, xb, y, yb, Wq, Wqt, Wkv, Wkvt, Wproj, Wprt);

    gemm_qkv<<<dim3(1728), dim3(256), 0, stream>>>(
        xb, Wqt, yb, Wkvt, Qbh, Kbh, Vtb, x_t, y_t, inv_freq);

    attn_mfma<<<dim3(TX_ / 64, B_ * H_), dim3(512), 0, stream>>>(
        Qbh, Kbh, Vtb, x_t, y_t, dist, min_dist, Ob);

    gemm_proj<<<dim3(192), dim3(256), 0, stream>>>(
        Ob, Wprt, out);
}